// Round 16
// baseline (367.037 us; speedup 1.0000x reference)
//
#include <hip/hip_runtime.h>

constexpr int kN  = 16384;
constexpr int kEB = 524288;
constexpr int kET = 262144;
constexpr int kTA = 107;
constexpr float kEps = 1e-5f;
#define HN 256

typedef __attribute__((ext_vector_type(8))) short short8;
typedef __attribute__((ext_vector_type(4))) float floatx4;
typedef unsigned short u16;
typedef unsigned int u32;

#define GLOAD_LDS16(gp, lp)                                                    \
  __builtin_amdgcn_global_load_lds(                                            \
      (const __attribute__((address_space(1))) u32*)(gp),                      \
      (__attribute__((address_space(3))) u32*)(lp), 16, 0, 0)

__device__ __forceinline__ u32 bf16rn(float f) {
  u32 u = __float_as_uint(f);
  return (u + 0x7FFFu + ((u >> 16) & 1u)) >> 16;
}
__device__ __forceinline__ u32 pack2(float a, float b) {
  return bf16rn(a) | (bf16rn(b) << 16);
}
__device__ __forceinline__ float bf2f(u32 v) {
  return __uint_as_float(v << 16);
}
__device__ __forceinline__ u32 cvtpk(float lo, float hi) {
  u32 r;
  asm("v_cvt_pk_bf16_f32 %0, %1, %2" : "=v"(r) : "v"(lo), "v"(hi));
  return r;
}
__device__ __forceinline__ void ub8(uint4 u, float* f) {
  f[0] = bf2f(u.x & 0xFFFF); f[1] = bf2f(u.x >> 16);
  f[2] = bf2f(u.y & 0xFFFF); f[3] = bf2f(u.y >> 16);
  f[4] = bf2f(u.z & 0xFFFF); f[5] = bf2f(u.z >> 16);
  f[6] = bf2f(u.w & 0xFFFF); f[7] = bf2f(u.w >> 16);
}
__device__ __forceinline__ u32 swz512(u32 b) { return b ^ (((b >> 9) & 7u) << 4); }

// ================= L1: pack weights + cvt x + zero deg/cnt =================
__global__ __launch_bounds__(256)
void k_prep_const(const float* __restrict__ w1, const float* __restrict__ Wb,
                  const float* __restrict__ Wt, const float* __restrict__ b1,
                  const float* __restrict__ pg, const float* __restrict__ pbeta,
                  const float* __restrict__ w2, u16* __restrict__ pk1,
                  u16* __restrict__ pkb, u16* __restrict__ pkt,
                  float4* __restrict__ pp, const float* __restrict__ x,
                  u16* __restrict__ xb, uint4* __restrict__ zero4) {
  int bid = blockIdx.x, tid = threadIdx.x;
  if (bid < 641) {
    int idx = bid * 256 + tid;
    if (idx < 32768) {                       // w1: K=128 padded from 107
      int e = idx & 7, lane = (idx >> 3) & 63, ct = (idx >> 9) & 15, kk = idx >> 13;
      int k = kk * 32 + (lane >> 4) * 8 + e, col = ct * 16 + (lane & 15);
      pk1[idx] = (u16)(k < kTA ? bf16rn(w1[(size_t)k * 256 + col]) : 0);
    } else if (idx < 163840) {
      int j = idx - 32768;
      const float* W = (j < 65536) ? Wb : Wt;
      u16* pk = (j < 65536) ? pkb : pkt;
      int t = j & 65535;
      int e = t & 7, lane = (t >> 3) & 63, ct = (t >> 9) & 15, kt = t >> 13;
      int k = kt * 32 + (lane >> 4) * 8 + e, col = ct * 16 + (lane & 15);
      pk[t] = (u16)bf16rn(W[(size_t)k * 256 + col]);
    } else if (idx < 163840 + 256) {
      int col = idx - 163840;
      pp[col] = make_float4(b1[col], pg[col], pbeta[col], w2[col]);
    }
  } else if (bid < 641 + 2048) {
    size_t i = (size_t)((bid - 641) * 256 + tid) * 8;
    float4 a = *(const float4*)(x + i);
    float4 b = *(const float4*)(x + i + 4);
    *(uint4*)(xb + i) = make_uint4(pack2(a.x, a.y), pack2(a.z, a.w),
                                   pack2(b.x, b.y), pack2(b.z, b.w));
  } else {
    zero4[(bid - 2689) * 256 + tid] = make_uint4(0, 0, 0, 0);
  }
}

// ================= roles =================
// proj role: r15 k_proj_mfma body (persistent B, pipelined tiles)
#define PROJ_TILES 4
__device__ __forceinline__
void proj_role(u16* Btile, const float* __restrict__ attr,
               const u16* __restrict__ pk1, const float* __restrict__ b1,
               const float4* __restrict__ pp, const float* __restrict__ b2,
               float* __restrict__ temp_w, int projid, int tid) {
  int w = tid >> 6, lane = tid & 63, low4 = lane & 15, hi = lane >> 4;

#pragma unroll
  for (int it = 0; it < 8; ++it) {
    int chunk = it * 512 + tid;
    GLOAD_LDS16((const char*)pk1 + (size_t)chunk * 16,
                (char*)Btile + (it * 512 + w * 64) * 16);
  }

  auto buildA = [&](int t, short8* a) {
    int e0 = (projid * PROJ_TILES + t) * 128 + w * 16;
    const float* rowp = attr + (size_t)(e0 + low4) * kTA;
#pragma unroll
    for (int kk = 0; kk < 4; ++kk) {
      int kb = kk * 32 + hi * 8;
      float v[8];
#pragma unroll
      for (int e = 0; e < 8; ++e)
        v[e] = (kk < 3 || kb + e < kTA) ? rowp[kb + e] : 0.f;
      union { short8 s8; uint4 u4; } fr;
      fr.u4 = make_uint4(cvtpk(v[0], v[1]), cvtpk(v[2], v[3]),
                         cvtpk(v[4], v[5]), cvtpk(v[6], v[7]));
      a[kk] = fr.s8;
    }
  };

  short8 a_cur[4];
  buildA(0, a_cur);
  float b2s = b2[0];

  __syncthreads();

#pragma unroll
  for (int t = 0; t < PROJ_TILES; ++t) {
    int e0 = (projid * PROJ_TILES + t) * 128 + w * 16;
    short8 a_next[4];
    if (t + 1 < PROJ_TILES) buildA(t + 1, a_next);

    u32 hvpk[16][2];
    float s1[4] = {0.f, 0.f, 0.f, 0.f}, s2[4] = {0.f, 0.f, 0.f, 0.f};
#pragma unroll
    for (int nn = 0; nn < 16; ++nn) {
      floatx4 acc = (floatx4){0.f, 0.f, 0.f, 0.f};
#pragma unroll
      for (int kk = 0; kk < 4; ++kk) {
        short8 bfr = *(const short8*)(Btile + ((size_t)(kk * 16 + nn) * 64 + lane) * 8);
        acc = __builtin_amdgcn_mfma_f32_16x16x32_bf16(a_cur[kk], bfr, acc, 0, 0, 0);
      }
      float b1v = b1[nn * 16 + low4];
      float h0 = acc[0] + b1v, h1 = acc[1] + b1v, h2 = acc[2] + b1v, h3 = acc[3] + b1v;
      s1[0] += h0; s2[0] += h0 * h0;
      s1[1] += h1; s2[1] += h1 * h1;
      s1[2] += h2; s2[2] += h2 * h2;
      s1[3] += h3; s2[3] += h3 * h3;
      hvpk[nn][0] = cvtpk(h0, h1);
      hvpk[nn][1] = cvtpk(h2, h3);
    }

    float mean[4], inv[4];
#pragma unroll
    for (int j = 0; j < 4; ++j) {
#pragma unroll
      for (int m = 1; m < 16; m <<= 1) {
        s1[j] += __shfl_xor(s1[j], m, 64);
        s2[j] += __shfl_xor(s2[j], m, 64);
      }
      mean[j] = s1[j] * (1.f / 256);
      inv[j] = rsqrtf(s2[j] * (1.f / 256) - mean[j] * mean[j] + kEps);
    }

    float d[4] = {0.f, 0.f, 0.f, 0.f};
#pragma unroll
    for (int nn = 0; nn < 16; ++nn) {
      float4 p = pp[nn * 16 + low4];
      float h0 = bf2f(hvpk[nn][0] & 0xFFFF);
      float h1 = bf2f(hvpk[nn][0] >> 16);
      float h2 = bf2f(hvpk[nn][1] & 0xFFFF);
      float h3 = bf2f(hvpk[nn][1] >> 16);
      d[0] += fmaxf((h0 - mean[0]) * inv[0] * p.y + p.z, 0.f) * p.w;
      d[1] += fmaxf((h1 - mean[1]) * inv[1] * p.y + p.z, 0.f) * p.w;
      d[2] += fmaxf((h2 - mean[2]) * inv[2] * p.y + p.z, 0.f) * p.w;
      d[3] += fmaxf((h3 - mean[3]) * inv[3] * p.y + p.z, 0.f) * p.w;
    }
#pragma unroll
    for (int j = 0; j < 4; ++j) {
#pragma unroll
      for (int m = 1; m < 16; m <<= 1) d[j] += __shfl_xor(d[j], m, 64);
      if (low4 == 0) temp_w[e0 + hi * 4 + j] = d[j] + b2s;
    }
#pragma unroll
    for (int kk = 0; kk < 4; ++kk) a_cur[kk] = a_next[kk];
  }
}

// gemm role: 64 rows/block (two 32-row halves), 512 threads, 32KB of shmem
__device__ __forceinline__
void gemm64_role(u16* shmem, const u16* __restrict__ Ab,
                 const u16* __restrict__ pkW, u16* __restrict__ Cb,
                 int gid, int tid) {
  int half = tid >> 8, t = tid & 255;
  int w = t >> 6, lane = t & 63, low4 = lane & 15, hi = lane >> 4;
  int row0 = gid * 64 + half * 32;
  u16* Atile = shmem + half * 8192;   // 32*256 u16 per half

  const char* asrc = (const char*)(Ab + (size_t)row0 * 256);
#pragma unroll
  for (int i = 0; i < 4; ++i) {
    u32 d = (u32)(((i * 4 + w) * 64 + lane) * 16);
    GLOAD_LDS16(asrc + swz512(d), (char*)Atile + (i * 4 + w) * 1024);
  }

  floatx4 acc[2][4];
#pragma unroll
  for (int rt = 0; rt < 2; ++rt)
#pragma unroll
    for (int nn = 0; nn < 4; ++nn) acc[rt][nn] = (floatx4){0.f, 0.f, 0.f, 0.f};

  __syncthreads();

#pragma unroll
  for (int kt = 0; kt < 8; ++kt) {
    short8 bfr[4];
    const u16* pw = pkW + ((size_t)(kt * 16 + w * 4) * 64 + lane) * 8;
#pragma unroll
    for (int nn = 0; nn < 4; ++nn) bfr[nn] = *(const short8*)(pw + nn * 512);
    short8 afr[2];
#pragma unroll
    for (int rt = 0; rt < 2; ++rt) {
      u32 p = (u32)((rt * 16 + low4) * 512 + (kt * 32 + hi * 8) * 2);
      afr[rt] = *(const short8*)((const char*)Atile + swz512(p));
    }
#pragma unroll
    for (int rt = 0; rt < 2; ++rt)
#pragma unroll
      for (int nn = 0; nn < 4; ++nn)
        acc[rt][nn] = __builtin_amdgcn_mfma_f32_16x16x32_bf16(afr[rt], bfr[nn],
                                                              acc[rt][nn], 0, 0, 0);
  }
#pragma unroll
  for (int rt = 0; rt < 2; ++rt)
#pragma unroll
    for (int nn = 0; nn < 4; ++nn)
#pragma unroll
      for (int j = 0; j < 4; ++j) {
        int row = row0 + rt * 16 + hi * 4 + j;
        int col = w * 64 + nn * 16 + low4;
        Cb[(size_t)row * 256 + col] = (u16)bf16rn(acc[rt][nn][j]);
      }
}

// scan role (256 threads): exclusive scan over kN counts + dis = rsqrt(deg+1)
__device__ __forceinline__
void scan_role(const int* __restrict__ cnt, int* __restrict__ base,
               int* __restrict__ cur, const float* __restrict__ deg,
               float* __restrict__ dis) {
  __shared__ int part[256];
  int tid = threadIdx.x;
  int per = kN >> 8;
  int i0 = tid * per;
  int s = 0;
  for (int k = 0; k < per; ++k) s += cnt[i0 + k];
  part[tid] = s;
  __syncthreads();
  for (int off = 1; off < 256; off <<= 1) {
    int v = (tid >= off) ? part[tid - off] : 0;
    __syncthreads();
    part[tid] += v;
    __syncthreads();
  }
  int run = (tid == 0) ? 0 : part[tid - 1];
  for (int k = 0; k < per; ++k) {
    base[i0 + k] = run; cur[i0 + k] = run; run += cnt[i0 + k];
    float d = deg[i0 + k] + 1.0f;
    dis[i0 + k] = (d > 0.f) ? rsqrtf(d) : 0.f;
  }
  if (tid == 255) base[kN] = run;
}

// agg role: 32 lanes/node, 8 nodes per 256-thread block
template <int FINAL>
__device__ __forceinline__
void agg_role(const u16* __restrict__ h, const void* __restrict__ residv,
              const float* __restrict__ x0, const int2* __restrict__ csr,
              const int* __restrict__ basep, const float* __restrict__ dis,
              const float* __restrict__ bias, const float* __restrict__ g1,
              const float* __restrict__ b1, const float* __restrict__ g2,
              const float* __restrict__ b2, void* __restrict__ outv, int aid) {
  int tid = threadIdx.x;
  int sub = tid >> 5, lane = tid & 31;
  int node = aid * 8 + sub;
  int c = lane * 8;
  const u16* hcol = h + c;
  float di = dis[node];
  float sl = di * di;
  float acc[8];
  {
    uint4 u = *(const uint4*)(hcol + (size_t)node * HN);
    float f[8]; ub8(u, f);
#pragma unroll
    for (int i = 0; i < 8; ++i) acc[i] = f[i] * sl;
  }
  int e0 = basep[node], e1 = basep[node + 1];
  int k = e0;
  for (; k + 4 <= e1; k += 4) {
    int2 p0 = csr[k], p1 = csr[k + 1], p2 = csr[k + 2], p3 = csr[k + 3];
    uint4 u0 = *(const uint4*)(hcol + (size_t)p0.x * HN);
    uint4 u1 = *(const uint4*)(hcol + (size_t)p1.x * HN);
    uint4 u2 = *(const uint4*)(hcol + (size_t)p2.x * HN);
    uint4 u3 = *(const uint4*)(hcol + (size_t)p3.x * HN);
    float n0 = __int_as_float(p0.y), n1 = __int_as_float(p1.y);
    float n2 = __int_as_float(p2.y), n3 = __int_as_float(p3.y);
    float f0[8], f1[8], f2[8], f3[8];
    ub8(u0, f0); ub8(u1, f1); ub8(u2, f2); ub8(u3, f3);
#pragma unroll
    for (int i = 0; i < 8; ++i)
      acc[i] += n0 * f0[i] + n1 * f1[i] + n2 * f2[i] + n3 * f3[i];
  }
  for (; k < e1; ++k) {
    int2 p = csr[k];
    uint4 u = *(const uint4*)(hcol + (size_t)p.x * HN);
    float nf = __int_as_float(p.y);
    float f[8]; ub8(u, f);
#pragma unroll
    for (int i = 0; i < 8; ++i) acc[i] += nf * f[i];
  }
  float v[8];
  {
    float4 b0 = *(const float4*)(bias + c);
    float4 b4 = *(const float4*)(bias + c + 4);
    float bb[8] = {b0.x, b0.y, b0.z, b0.w, b4.x, b4.y, b4.z, b4.w};
    float rr[8];
    if (!FINAL) {
      const float* rp = (const float*)residv + (size_t)node * HN + c;
      float4 r0 = *(const float4*)rp;
      float4 r4 = *(const float4*)(rp + 4);
      rr[0] = r0.x; rr[1] = r0.y; rr[2] = r0.z; rr[3] = r0.w;
      rr[4] = r4.x; rr[5] = r4.y; rr[6] = r4.z; rr[7] = r4.w;
    } else {
      uint4 u = *(const uint4*)((const u16*)residv + (size_t)node * HN + c);
      ub8(u, rr);
    }
#pragma unroll
    for (int i = 0; i < 8; ++i) v[i] = acc[i] + bb[i] + rr[i];
  }
  float s1 = 0.f, s2 = 0.f;
#pragma unroll
  for (int i = 0; i < 8; ++i) { s1 += v[i]; s2 += v[i] * v[i]; }
#pragma unroll
  for (int m = 1; m < 32; m <<= 1) {
    s1 += __shfl_xor(s1, m, 64);
    s2 += __shfl_xor(s2, m, 64);
  }
  float mean = s1 * (1.f / HN);
  float inv = rsqrtf(s2 * (1.f / HN) - mean * mean + kEps);
  float4 ga = *(const float4*)(g1 + c);
  float4 gb = *(const float4*)(g1 + c + 4);
  float4 ba = *(const float4*)(b1 + c);
  float4 bbv = *(const float4*)(b1 + c + 4);
  float gg[8] = {ga.x, ga.y, ga.z, ga.w, gb.x, gb.y, gb.z, gb.w};
  float bt[8] = {ba.x, ba.y, ba.z, ba.w, bbv.x, bbv.y, bbv.z, bbv.w};
  float y[8];
#pragma unroll
  for (int i = 0; i < 8; ++i)
    y[i] = fmaxf((v[i] - mean) * inv * gg[i] + bt[i], 0.f);
  if (!FINAL) {
    uint4 o = make_uint4(cvtpk(y[0], y[1]), cvtpk(y[2], y[3]),
                         cvtpk(y[4], y[5]), cvtpk(y[6], y[7]));
    *(uint4*)((u16*)outv + (size_t)node * HN + c) = o;
  } else {
    const float* xp = x0 + (size_t)node * HN + c;
    float4 x0v = *(const float4*)xp;
    float4 x4v = *(const float4*)(xp + 4);
    float xx[8] = {x0v.x, x0v.y, x0v.z, x0v.w, x4v.x, x4v.y, x4v.z, x4v.w};
    float z[8];
    float t1 = 0.f, t2 = 0.f;
#pragma unroll
    for (int i = 0; i < 8; ++i) {
      z[i] = y[i] + xx[i];
      t1 += z[i]; t2 += z[i] * z[i];
    }
#pragma unroll
    for (int m = 1; m < 32; m <<= 1) {
      t1 += __shfl_xor(t1, m, 64);
      t2 += __shfl_xor(t2, m, 64);
    }
    float m2 = t1 * (1.f / HN);
    float i2 = rsqrtf(t2 * (1.f / HN) - m2 * m2 + kEps);
    float4 Ga = *(const float4*)(g2 + c);
    float4 Gb = *(const float4*)(g2 + c + 4);
    float4 Ba = *(const float4*)(b2 + c);
    float4 Bb = *(const float4*)(b2 + c + 4);
    float G[8] = {Ga.x, Ga.y, Ga.z, Ga.w, Gb.x, Gb.y, Gb.z, Gb.w};
    float B[8] = {Ba.x, Ba.y, Ba.z, Ba.w, Bb.x, Bb.y, Bb.z, Bb.w};
    float* op = (float*)outv + (size_t)node * HN + c;
    *(float4*)op = make_float4((z[0] - m2) * i2 * G[0] + B[0],
                               (z[1] - m2) * i2 * G[1] + B[1],
                               (z[2] - m2) * i2 * G[2] + B[2],
                               (z[3] - m2) * i2 * G[3] + B[3]);
    *(float4*)(op + 4) = make_float4((z[4] - m2) * i2 * G[4] + B[4],
                                     (z[5] - m2) * i2 * G[5] + B[5],
                                     (z[6] - m2) * i2 * G[6] + B[6],
                                     (z[7] - m2) * i2 * G[7] + B[7]);
  }
}

// ================= L2: ÜBER — proj ∥ gemm1 ∥ bold edge-prep =================
// Round-striped roles (stripes of 256 blocks) so round-robin block->CU
// assignment co-schedules 1 proj block + 1 other block per CU.
__global__ __launch_bounds__(512)
void k_uber1(const float* __restrict__ attr, const u16* __restrict__ pk1,
             const float* __restrict__ b1, const float4* __restrict__ pp,
             const float* __restrict__ b2, float* __restrict__ temp_w,
             const u16* __restrict__ xb, const u16* __restrict__ pkb,
             u16* __restrict__ hb, const int* __restrict__ bcol,
             const float* __restrict__ bw, float* __restrict__ deg_b,
             int* __restrict__ cnt_b) {
  __shared__ __align__(16) u16 shmem[32768];   // 64 KB
  int bid = blockIdx.x, tid = threadIdx.x;
  int r = bid >> 8, idx = bid & 255;
  if (r == 0 || r == 2) {
    proj_role(shmem, attr, pk1, b1, pp, b2, temp_w, idx + (r == 2 ? 256 : 0), tid);
  } else if (r == 1) {
    gemm64_role(shmem, xb, pkb, hb, idx, tid);
  } else {
    int eid = ((r - 3) * 256 + idx) * 512 + tid;
    if (eid < kEB) {
      int c = bcol[eid];
      atomicAdd(&deg_b[c], bw[eid]);
      atomicAdd(&cnt_b[c], 1);
    }
  }
}

// ================= L3: scan_b ∥ temporal edge-prep =================
__global__ __launch_bounds__(256)
void k_scanb_prept(const int* __restrict__ cnt_b, int* __restrict__ base_b,
                   int* __restrict__ cur_b, const float* __restrict__ deg_b,
                   float* __restrict__ dis_b, const int* __restrict__ tcol,
                   const float* __restrict__ tmpw, float* __restrict__ deg_t,
                   int* __restrict__ cnt_t) {
  if (blockIdx.x == 0) {
    scan_role(cnt_b, base_b, cur_b, deg_b, dis_b);
  } else {
    int eid = (blockIdx.x - 1) * 256 + threadIdx.x;
    int c = tcol[eid];
    atomicAdd(&deg_t[c], tmpw[eid]);
    atomicAdd(&cnt_t[c], 1);
  }
}

// ================= L4: fill_b ∥ scan_t =================
__global__ __launch_bounds__(256)
void k_fillb_scant(const int* __restrict__ bei, const float* __restrict__ bw,
                   const float* __restrict__ dis_b, int* __restrict__ cur_b,
                   int2* __restrict__ csr_b, const int* __restrict__ cnt_t,
                   int* __restrict__ base_t, int* __restrict__ cur_t,
                   const float* __restrict__ deg_t, float* __restrict__ dis_t) {
  if (blockIdx.x == 0) {
    scan_role(cnt_t, base_t, cur_t, deg_t, dis_t);
  } else {
    int eid = (blockIdx.x - 1) * 256 + threadIdx.x;
    int rr = bei[eid], c = bei[kEB + eid];
    float nrm = dis_b[rr] * bw[eid] * dis_b[c];
    int pos = atomicAdd(&cur_b[c], 1);
    csr_b[pos] = make_int2(rr, __float_as_int(nrm));
  }
}

// ================= L5: agg0 ∥ fill_t (round-striped) =================
__global__ __launch_bounds__(256)
void k_agg0_fillt(const u16* __restrict__ hb, const float* __restrict__ x,
                  const int2* __restrict__ csr_b, const int* __restrict__ base_b,
                  const float* __restrict__ dis_b, const float* __restrict__ bbias,
                  const float* __restrict__ gs, const float* __restrict__ bs,
                  u16* __restrict__ sb, const int* __restrict__ tei,
                  const float* __restrict__ tmpw, const float* __restrict__ dis_t,
                  int* __restrict__ cur_t, int2* __restrict__ csr_t) {
  int bid = blockIdx.x;
  int r = bid >> 8, idx = bid & 255;
  if (r % 3 == 1) {                           // 4 rounds x 256 = 1024 fill blocks
    int eid = ((r / 3) * 256 + idx) * 256 + threadIdx.x;
    int rr = tei[eid], c = tei[kET + eid];
    float nrm = dis_t[rr] * tmpw[eid] * dis_t[c];
    int pos = atomicAdd(&cur_t[c], 1);
    csr_t[pos] = make_int2(rr, __float_as_int(nrm));
  } else {                                    // 8 rounds x 256 = 2048 agg blocks
    int agg_ord = r - r / 3 - (r % 3 == 2 ? 1 : 0);
    agg_role<0>(hb, x, nullptr, csr_b, base_b, dis_b, bbias, gs, bs,
                nullptr, nullptr, sb, agg_ord * 256 + idx);
  }
}

// ================= L6: gemm2 (standalone, 32 rows/block) =================
__global__ __launch_bounds__(256)
void k_gemm_mfma(const u16* __restrict__ Ab, const u16* __restrict__ pkW,
                 u16* __restrict__ Cb) {
  __shared__ __align__(16) u16 Atile[32 * 256];
  int tid = threadIdx.x;
  int w = tid >> 6, lane = tid & 63, low4 = lane & 15, hi = lane >> 4;
  int row0 = blockIdx.x * 32;

  const char* asrc = (const char*)(Ab + (size_t)row0 * 256);
#pragma unroll
  for (int i = 0; i < 4; ++i) {
    u32 d = (u32)(((i * 4 + w) * 64 + lane) * 16);
    GLOAD_LDS16(asrc + swz512(d), (char*)Atile + (i * 4 + w) * 1024);
  }

  floatx4 acc[2][4];
#pragma unroll
  for (int rt = 0; rt < 2; ++rt)
#pragma unroll
    for (int nn = 0; nn < 4; ++nn) acc[rt][nn] = (floatx4){0.f, 0.f, 0.f, 0.f};

  __syncthreads();

#pragma unroll
  for (int kt = 0; kt < 8; ++kt) {
    short8 bfr[4];
    const u16* pw = pkW + ((size_t)(kt * 16 + w * 4) * 64 + lane) * 8;
#pragma unroll
    for (int nn = 0; nn < 4; ++nn) bfr[nn] = *(const short8*)(pw + nn * 512);
    short8 afr[2];
#pragma unroll
    for (int rt = 0; rt < 2; ++rt) {
      u32 p = (u32)((rt * 16 + low4) * 512 + (kt * 32 + hi * 8) * 2);
      afr[rt] = *(const short8*)((const char*)Atile + swz512(p));
    }
#pragma unroll
    for (int rt = 0; rt < 2; ++rt)
#pragma unroll
      for (int nn = 0; nn < 4; ++nn)
        acc[rt][nn] = __builtin_amdgcn_mfma_f32_16x16x32_bf16(afr[rt], bfr[nn],
                                                              acc[rt][nn], 0, 0, 0);
  }
#pragma unroll
  for (int rt = 0; rt < 2; ++rt)
#pragma unroll
    for (int nn = 0; nn < 4; ++nn)
#pragma unroll
      for (int j = 0; j < 4; ++j) {
        int row = row0 + rt * 16 + hi * 4 + j;
        int col = w * 64 + nn * 16 + low4;
        Cb[(size_t)row * 256 + col] = (u16)bf16rn(acc[rt][nn][j]);
      }
}

// ================= L7: agg1 (final) =================
__global__ __launch_bounds__(256)
void k_agg1(const u16* __restrict__ h, const u16* __restrict__ sb,
            const float* __restrict__ x0, const int2* __restrict__ csr,
            const int* __restrict__ basep, const float* __restrict__ dis,
            const float* __restrict__ bias, const float* __restrict__ g1,
            const float* __restrict__ b1, const float* __restrict__ g2,
            const float* __restrict__ b2, float* __restrict__ outp) {
  agg_role<1>(h, sb, x0, csr, basep, dis, bias, g1, b1, g2, b2, outp, blockIdx.x);
}

extern "C" void kernel_launch(void* const* d_in, const int* in_sizes, int n_in,
                              void* d_out, int out_size, void* d_ws, size_t ws_size,
                              hipStream_t stream) {
  const float* x     = (const float*)d_in[0];
  const int*   bei   = (const int*)d_in[1];
  const float* bew   = (const float*)d_in[2];
  const int*   tei   = (const int*)d_in[3];
  const float* tattr = (const float*)d_in[4];
  const float* Wb    = (const float*)d_in[5];
  const float* bb    = (const float*)d_in[6];
  const float* Wt    = (const float*)d_in[7];
  const float* bt    = (const float*)d_in[8];
  const float* gs    = (const float*)d_in[9];
  const float* bs    = (const float*)d_in[10];
  const float* gt    = (const float*)d_in[11];
  const float* btn   = (const float*)d_in[12];
  const float* pw1   = (const float*)d_in[13];
  const float* pb1   = (const float*)d_in[14];
  const float* pg    = (const float*)d_in[15];
  const float* pbeta = (const float*)d_in[16];
  const float* pw2   = (const float*)d_in[17];
  const float* pb2   = (const float*)d_in[18];
  float* outp = (float*)d_out;

  size_t off = 0;
  auto alloc = [&](size_t bytes) -> void* {
    void* p = (char*)d_ws + off;
    off += (bytes + 255) & ~(size_t)255;
    return p;
  };
  float* deg_b = (float*)alloc(kN * 4);
  float* deg_t = (float*)alloc(kN * 4);
  int*   cnt_b = (int*)alloc(kN * 4);
  int*   cnt_t = (int*)alloc(kN * 4);       // deg_b..cnt_t contiguous: zero-role
  float* dis_b = (float*)alloc(kN * 4);
  float* dis_t = (float*)alloc(kN * 4);
  int*   base_b = (int*)alloc((kN + 1) * 4);
  int*   base_t = (int*)alloc((kN + 1) * 4);
  int*   cur_b  = (int*)alloc(kN * 4);
  int*   cur_t  = (int*)alloc(kN * 4);
  float* tmpw   = (float*)alloc(kET * 4);
  int2*  csr_b  = (int2*)alloc((size_t)kEB * 8);
  int2*  csr_t  = (int2*)alloc((size_t)kET * 8);
  u16*   pk1 = (u16*)alloc(32768 * 2);
  u16*   pkb = (u16*)alloc(65536 * 2);
  u16*   pkt = (u16*)alloc(65536 * 2);
  float4* pp = (float4*)alloc(256 * 16);
  u16*   xb  = (u16*)alloc((size_t)kN * HN * 2);
  u16*   hb  = (u16*)alloc((size_t)kN * HN * 2);
  u16*   sb  = (u16*)alloc((size_t)kN * HN * 2);
  (void)ws_size; (void)in_sizes; (void)n_in; (void)out_size;

  // L1: pack ∥ cvt ∥ zero(deg_b..cnt_t)
  k_prep_const<<<2753, 256, 0, stream>>>(pw1, Wb, Wt, pb1, pg, pbeta, pw2,
                                         pk1, pkb, pkt, pp, x, xb,
                                         (uint4*)deg_b);
  // L2: proj ∥ gemm1 ∥ bold edge-prep
  k_uber1<<<1792, 512, 0, stream>>>(tattr, pk1, pb1, pp, pb2, tmpw,
                                    xb, pkb, hb, bei + kEB, bew, deg_b, cnt_b);
  // L3: scan_b ∥ temporal edge-prep
  k_scanb_prept<<<1 + kET / 256, 256, 0, stream>>>(cnt_b, base_b, cur_b, deg_b,
                                                   dis_b, tei + kET, tmpw,
                                                   deg_t, cnt_t);
  // L4: fill_b ∥ scan_t
  k_fillb_scant<<<1 + kEB / 256, 256, 0, stream>>>(bei, bew, dis_b, cur_b, csr_b,
                                                   cnt_t, base_t, cur_t,
                                                   deg_t, dis_t);
  // L5: agg0 ∥ fill_t
  k_agg0_fillt<<<3072, 256, 0, stream>>>(hb, x, csr_b, base_b, dis_b, bb, gs, bs,
                                         sb, tei, tmpw, dis_t, cur_t, csr_t);
  // L6: gemm2
  k_gemm_mfma<<<kN / 32, 256, 0, stream>>>(sb, pkt, hb);
  // L7: agg1 + final LN
  k_agg1<<<kN / 8, 256, 0, stream>>>(hb, sb, x, csr_t, base_t, dis_t,
                                     bt, gt, btn, gs, bs, outp);
}

// Round 17
// 266.516 us; speedup vs baseline: 1.3772x; 1.3772x over previous
//
#include <hip/hip_runtime.h>

constexpr int kN  = 16384;
constexpr int kEB = 524288;
constexpr int kET = 262144;
constexpr int kTA = 107;
constexpr float kEps = 1e-5f;
#define HN 256

typedef __attribute__((ext_vector_type(8))) short short8;
typedef __attribute__((ext_vector_type(4))) float floatx4;
typedef unsigned short u16;
typedef unsigned int u32;

#define GLOAD_LDS16(gp, lp)                                                    \
  __builtin_amdgcn_global_load_lds(                                            \
      (const __attribute__((address_space(1))) u32*)(gp),                      \
      (__attribute__((address_space(3))) u32*)(lp), 16, 0, 0)

__device__ __forceinline__ u32 bf16rn(float f) {
  u32 u = __float_as_uint(f);
  return (u + 0x7FFFu + ((u >> 16) & 1u)) >> 16;
}
__device__ __forceinline__ u32 pack2(float a, float b) {
  return bf16rn(a) | (bf16rn(b) << 16);
}
__device__ __forceinline__ float bf2f(u32 v) {
  return __uint_as_float(v << 16);
}
__device__ __forceinline__ u32 cvtpk(float lo, float hi) {
  u32 r;
  asm("v_cvt_pk_bf16_f32 %0, %1, %2" : "=v"(r) : "v"(lo), "v"(hi));
  return r;
}
__device__ __forceinline__ void ub8(uint4 u, float* f) {
  f[0] = bf2f(u.x & 0xFFFF); f[1] = bf2f(u.x >> 16);
  f[2] = bf2f(u.y & 0xFFFF); f[3] = bf2f(u.y >> 16);
  f[4] = bf2f(u.z & 0xFFFF); f[5] = bf2f(u.z >> 16);
  f[6] = bf2f(u.w & 0xFFFF); f[7] = bf2f(u.w >> 16);
}
__device__ __forceinline__ u32 swz512(u32 b) { return b ^ (((b >> 9) & 7u) << 4); }

// ================= L1: pack weights ∥ cvt x ∥ zero deg/cnt =================
__global__ __launch_bounds__(256)
void k_prep_const(const float* __restrict__ w1, const float* __restrict__ Wb,
                  const float* __restrict__ Wt, const float* __restrict__ b1,
                  const float* __restrict__ pg, const float* __restrict__ pbeta,
                  const float* __restrict__ w2, u16* __restrict__ pk1,
                  u16* __restrict__ pkb, u16* __restrict__ pkt,
                  float4* __restrict__ pp, const float* __restrict__ x,
                  u16* __restrict__ xb, uint4* __restrict__ zero4) {
  int bid = blockIdx.x, tid = threadIdx.x;
  if (bid < 641) {
    int idx = bid * 256 + tid;
    if (idx < 32768) {                       // w1: K=128 padded from 107
      int e = idx & 7, lane = (idx >> 3) & 63, ct = (idx >> 9) & 15, kk = idx >> 13;
      int k = kk * 32 + (lane >> 4) * 8 + e, col = ct * 16 + (lane & 15);
      pk1[idx] = (u16)(k < kTA ? bf16rn(w1[(size_t)k * 256 + col]) : 0);
    } else if (idx < 163840) {
      int j = idx - 32768;
      const float* W = (j < 65536) ? Wb : Wt;
      u16* pk = (j < 65536) ? pkb : pkt;
      int t = j & 65535;
      int e = t & 7, lane = (t >> 3) & 63, ct = (t >> 9) & 15, kt = t >> 13;
      int k = kt * 32 + (lane >> 4) * 8 + e, col = ct * 16 + (lane & 15);
      pk[t] = (u16)bf16rn(W[(size_t)k * 256 + col]);
    } else if (idx < 163840 + 256) {
      int col = idx - 163840;
      pp[col] = make_float4(b1[col], pg[col], pbeta[col], w2[col]);
    }
  } else if (bid < 641 + 2048) {
    size_t i = (size_t)((bid - 641) * 256 + tid) * 8;
    float4 a = *(const float4*)(x + i);
    float4 b = *(const float4*)(x + i + 4);
    *(uint4*)(xb + i) = make_uint4(pack2(a.x, a.y), pack2(a.z, a.w),
                                   pack2(b.x, b.y), pack2(b.z, b.w));
  } else {
    zero4[(bid - 2689) * 256 + tid] = make_uint4(0, 0, 0, 0);
  }
}

// ============ proj: persistent B, 512-thr, pipelined tiles (r15) ============
#define PROJ_TILES 4
__global__ __launch_bounds__(512)
void k_proj_mfma(const float* __restrict__ attr, const u16* __restrict__ pk1,
                 const float* __restrict__ b1, const float4* __restrict__ pp,
                 const float* __restrict__ b2, float* __restrict__ temp_w) {
  __shared__ __align__(16) u16 Btile[32768];   // 64 KB = whole packed w1
  int tid = threadIdx.x;
  int w = tid >> 6, lane = tid & 63, low4 = lane & 15, hi = lane >> 4;

#pragma unroll
  for (int it = 0; it < 8; ++it) {
    int chunk = it * 512 + tid;
    GLOAD_LDS16((const char*)pk1 + (size_t)chunk * 16,
                (char*)Btile + (it * 512 + w * 64) * 16);
  }

  auto buildA = [&](int t, short8* a) {
    int e0 = (blockIdx.x * PROJ_TILES + t) * 128 + w * 16;
    const float* rowp = attr + (size_t)(e0 + low4) * kTA;
#pragma unroll
    for (int kk = 0; kk < 4; ++kk) {
      int kb = kk * 32 + hi * 8;
      float v[8];
#pragma unroll
      for (int e = 0; e < 8; ++e)
        v[e] = (kk < 3 || kb + e < kTA) ? rowp[kb + e] : 0.f;
      union { short8 s8; uint4 u4; } fr;
      fr.u4 = make_uint4(cvtpk(v[0], v[1]), cvtpk(v[2], v[3]),
                         cvtpk(v[4], v[5]), cvtpk(v[6], v[7]));
      a[kk] = fr.s8;
    }
  };

  short8 a_cur[4];
  buildA(0, a_cur);
  float b2s = b2[0];

  __syncthreads();

#pragma unroll
  for (int t = 0; t < PROJ_TILES; ++t) {
    int e0 = (blockIdx.x * PROJ_TILES + t) * 128 + w * 16;
    short8 a_next[4];
    if (t + 1 < PROJ_TILES) buildA(t + 1, a_next);

    u32 hvpk[16][2];
    float s1[4] = {0.f, 0.f, 0.f, 0.f}, s2[4] = {0.f, 0.f, 0.f, 0.f};
#pragma unroll
    for (int nn = 0; nn < 16; ++nn) {
      floatx4 acc = (floatx4){0.f, 0.f, 0.f, 0.f};
#pragma unroll
      for (int kk = 0; kk < 4; ++kk) {
        short8 bfr = *(const short8*)(Btile + ((size_t)(kk * 16 + nn) * 64 + lane) * 8);
        acc = __builtin_amdgcn_mfma_f32_16x16x32_bf16(a_cur[kk], bfr, acc, 0, 0, 0);
      }
      float b1v = b1[nn * 16 + low4];
      float h0 = acc[0] + b1v, h1 = acc[1] + b1v, h2 = acc[2] + b1v, h3 = acc[3] + b1v;
      s1[0] += h0; s2[0] += h0 * h0;
      s1[1] += h1; s2[1] += h1 * h1;
      s1[2] += h2; s2[2] += h2 * h2;
      s1[3] += h3; s2[3] += h3 * h3;
      hvpk[nn][0] = cvtpk(h0, h1);
      hvpk[nn][1] = cvtpk(h2, h3);
    }

    float mean[4], inv[4];
#pragma unroll
    for (int j = 0; j < 4; ++j) {
#pragma unroll
      for (int m = 1; m < 16; m <<= 1) {
        s1[j] += __shfl_xor(s1[j], m, 64);
        s2[j] += __shfl_xor(s2[j], m, 64);
      }
      mean[j] = s1[j] * (1.f / 256);
      inv[j] = rsqrtf(s2[j] * (1.f / 256) - mean[j] * mean[j] + kEps);
    }

    float d[4] = {0.f, 0.f, 0.f, 0.f};
#pragma unroll
    for (int nn = 0; nn < 16; ++nn) {
      float4 p = pp[nn * 16 + low4];
      float h0 = bf2f(hvpk[nn][0] & 0xFFFF);
      float h1 = bf2f(hvpk[nn][0] >> 16);
      float h2 = bf2f(hvpk[nn][1] & 0xFFFF);
      float h3 = bf2f(hvpk[nn][1] >> 16);
      d[0] += fmaxf((h0 - mean[0]) * inv[0] * p.y + p.z, 0.f) * p.w;
      d[1] += fmaxf((h1 - mean[1]) * inv[1] * p.y + p.z, 0.f) * p.w;
      d[2] += fmaxf((h2 - mean[2]) * inv[2] * p.y + p.z, 0.f) * p.w;
      d[3] += fmaxf((h3 - mean[3]) * inv[3] * p.y + p.z, 0.f) * p.w;
    }
#pragma unroll
    for (int j = 0; j < 4; ++j) {
#pragma unroll
      for (int m = 1; m < 16; m <<= 1) d[j] += __shfl_xor(d[j], m, 64);
      if (low4 == 0) temp_w[e0 + hi * 4 + j] = d[j] + b2s;
    }
#pragma unroll
    for (int kk = 0; kk < 4; ++kk) a_cur[kk] = a_next[kk];
  }
}

// ============ bold edge-prep (standalone) ============
__global__ __launch_bounds__(256)
void k_edge_prep_b(const int* __restrict__ bcol, const float* __restrict__ bw,
                   float* __restrict__ deg_b, int* __restrict__ cnt_b) {
  int e = blockIdx.x * 256 + threadIdx.x;
  int c = bcol[e];
  atomicAdd(&deg_b[c], bw[e]);
  atomicAdd(&cnt_b[c], 1);
}

// ============ scan role (256 threads) ============
__device__ __forceinline__
void scan_role(const int* __restrict__ cnt, int* __restrict__ base,
               int* __restrict__ cur, const float* __restrict__ deg,
               float* __restrict__ dis) {
  __shared__ int part[256];
  int tid = threadIdx.x;
  int per = kN >> 8;
  int i0 = tid * per;
  int s = 0;
  for (int k = 0; k < per; ++k) s += cnt[i0 + k];
  part[tid] = s;
  __syncthreads();
  for (int off = 1; off < 256; off <<= 1) {
    int v = (tid >= off) ? part[tid - off] : 0;
    __syncthreads();
    part[tid] += v;
    __syncthreads();
  }
  int run = (tid == 0) ? 0 : part[tid - 1];
  for (int k = 0; k < per; ++k) {
    base[i0 + k] = run; cur[i0 + k] = run; run += cnt[i0 + k];
    float d = deg[i0 + k] + 1.0f;
    dis[i0 + k] = (d > 0.f) ? rsqrtf(d) : 0.f;
  }
  if (tid == 255) base[kN] = run;
}

// ============ agg role: 32 lanes/node, 8 nodes per 256-thread block ============
template <int FINAL>
__device__ __forceinline__
void agg_role(const u16* __restrict__ h, const void* __restrict__ residv,
              const float* __restrict__ x0, const int2* __restrict__ csr,
              const int* __restrict__ basep, const float* __restrict__ dis,
              const float* __restrict__ bias, const float* __restrict__ g1,
              const float* __restrict__ b1, const float* __restrict__ g2,
              const float* __restrict__ b2, void* __restrict__ outv, int aid) {
  int tid = threadIdx.x;
  int sub = tid >> 5, lane = tid & 31;
  int node = aid * 8 + sub;
  int c = lane * 8;
  const u16* hcol = h + c;
  float di = dis[node];
  float sl = di * di;
  float acc[8];
  {
    uint4 u = *(const uint4*)(hcol + (size_t)node * HN);
    float f[8]; ub8(u, f);
#pragma unroll
    for (int i = 0; i < 8; ++i) acc[i] = f[i] * sl;
  }
  int e0 = basep[node], e1 = basep[node + 1];
  int k = e0;
  for (; k + 4 <= e1; k += 4) {
    int2 p0 = csr[k], p1 = csr[k + 1], p2 = csr[k + 2], p3 = csr[k + 3];
    uint4 u0 = *(const uint4*)(hcol + (size_t)p0.x * HN);
    uint4 u1 = *(const uint4*)(hcol + (size_t)p1.x * HN);
    uint4 u2 = *(const uint4*)(hcol + (size_t)p2.x * HN);
    uint4 u3 = *(const uint4*)(hcol + (size_t)p3.x * HN);
    float n0 = __int_as_float(p0.y), n1 = __int_as_float(p1.y);
    float n2 = __int_as_float(p2.y), n3 = __int_as_float(p3.y);
    float f0[8], f1[8], f2[8], f3[8];
    ub8(u0, f0); ub8(u1, f1); ub8(u2, f2); ub8(u3, f3);
#pragma unroll
    for (int i = 0; i < 8; ++i)
      acc[i] += n0 * f0[i] + n1 * f1[i] + n2 * f2[i] + n3 * f3[i];
  }
  for (; k < e1; ++k) {
    int2 p = csr[k];
    uint4 u = *(const uint4*)(hcol + (size_t)p.x * HN);
    float nf = __int_as_float(p.y);
    float f[8]; ub8(u, f);
#pragma unroll
    for (int i = 0; i < 8; ++i) acc[i] += nf * f[i];
  }
  float v[8];
  {
    float4 b0 = *(const float4*)(bias + c);
    float4 b4 = *(const float4*)(bias + c + 4);
    float bb[8] = {b0.x, b0.y, b0.z, b0.w, b4.x, b4.y, b4.z, b4.w};
    float rr[8];
    if (!FINAL) {
      const float* rp = (const float*)residv + (size_t)node * HN + c;
      float4 r0 = *(const float4*)rp;
      float4 r4 = *(const float4*)(rp + 4);
      rr[0] = r0.x; rr[1] = r0.y; rr[2] = r0.z; rr[3] = r0.w;
      rr[4] = r4.x; rr[5] = r4.y; rr[6] = r4.z; rr[7] = r4.w;
    } else {
      uint4 u = *(const uint4*)((const u16*)residv + (size_t)node * HN + c);
      ub8(u, rr);
    }
#pragma unroll
    for (int i = 0; i < 8; ++i) v[i] = acc[i] + bb[i] + rr[i];
  }
  float s1 = 0.f, s2 = 0.f;
#pragma unroll
  for (int i = 0; i < 8; ++i) { s1 += v[i]; s2 += v[i] * v[i]; }
#pragma unroll
  for (int m = 1; m < 32; m <<= 1) {
    s1 += __shfl_xor(s1, m, 64);
    s2 += __shfl_xor(s2, m, 64);
  }
  float mean = s1 * (1.f / HN);
  float inv = rsqrtf(s2 * (1.f / HN) - mean * mean + kEps);
  float4 ga = *(const float4*)(g1 + c);
  float4 gb = *(const float4*)(g1 + c + 4);
  float4 ba = *(const float4*)(b1 + c);
  float4 bbv = *(const float4*)(b1 + c + 4);
  float gg[8] = {ga.x, ga.y, ga.z, ga.w, gb.x, gb.y, gb.z, gb.w};
  float bt[8] = {ba.x, ba.y, ba.z, ba.w, bbv.x, bbv.y, bbv.z, bbv.w};
  float y[8];
#pragma unroll
  for (int i = 0; i < 8; ++i)
    y[i] = fmaxf((v[i] - mean) * inv * gg[i] + bt[i], 0.f);
  if (!FINAL) {
    uint4 o = make_uint4(cvtpk(y[0], y[1]), cvtpk(y[2], y[3]),
                         cvtpk(y[4], y[5]), cvtpk(y[6], y[7]));
    *(uint4*)((u16*)outv + (size_t)node * HN + c) = o;
  } else {
    const float* xp = x0 + (size_t)node * HN + c;
    float4 x0v = *(const float4*)xp;
    float4 x4v = *(const float4*)(xp + 4);
    float xx[8] = {x0v.x, x0v.y, x0v.z, x0v.w, x4v.x, x4v.y, x4v.z, x4v.w};
    float z[8];
    float t1 = 0.f, t2 = 0.f;
#pragma unroll
    for (int i = 0; i < 8; ++i) {
      z[i] = y[i] + xx[i];
      t1 += z[i]; t2 += z[i] * z[i];
    }
#pragma unroll
    for (int m = 1; m < 32; m <<= 1) {
      t1 += __shfl_xor(t1, m, 64);
      t2 += __shfl_xor(t2, m, 64);
    }
    float m2 = t1 * (1.f / HN);
    float i2 = rsqrtf(t2 * (1.f / HN) - m2 * m2 + kEps);
    float4 Ga = *(const float4*)(g2 + c);
    float4 Gb = *(const float4*)(g2 + c + 4);
    float4 Ba = *(const float4*)(b2 + c);
    float4 Bb = *(const float4*)(b2 + c + 4);
    float G[8] = {Ga.x, Ga.y, Ga.z, Ga.w, Gb.x, Gb.y, Gb.z, Gb.w};
    float B[8] = {Ba.x, Ba.y, Ba.z, Ba.w, Bb.x, Bb.y, Bb.z, Bb.w};
    float* op = (float*)outv + (size_t)node * HN + c;
    *(float4*)op = make_float4((z[0] - m2) * i2 * G[0] + B[0],
                               (z[1] - m2) * i2 * G[1] + B[1],
                               (z[2] - m2) * i2 * G[2] + B[2],
                               (z[3] - m2) * i2 * G[3] + B[3]);
    *(float4*)(op + 4) = make_float4((z[4] - m2) * i2 * G[4] + B[4],
                                     (z[5] - m2) * i2 * G[5] + B[5],
                                     (z[6] - m2) * i2 * G[6] + B[6],
                                     (z[7] - m2) * i2 * G[7] + B[7]);
  }
}

// ================= L3: scan_b ∥ temporal edge-prep =================
__global__ __launch_bounds__(256)
void k_scanb_prept(const int* __restrict__ cnt_b, int* __restrict__ base_b,
                   int* __restrict__ cur_b, const float* __restrict__ deg_b,
                   float* __restrict__ dis_b, const int* __restrict__ tcol,
                   const float* __restrict__ tmpw, float* __restrict__ deg_t,
                   int* __restrict__ cnt_t) {
  if (blockIdx.x == 0) {
    scan_role(cnt_b, base_b, cur_b, deg_b, dis_b);
  } else {
    int eid = (blockIdx.x - 1) * 256 + threadIdx.x;
    int c = tcol[eid];
    atomicAdd(&deg_t[c], tmpw[eid]);
    atomicAdd(&cnt_t[c], 1);
  }
}

// ================= L4: fill_b ∥ scan_t =================
__global__ __launch_bounds__(256)
void k_fillb_scant(const int* __restrict__ bei, const float* __restrict__ bw,
                   const float* __restrict__ dis_b, int* __restrict__ cur_b,
                   int2* __restrict__ csr_b, const int* __restrict__ cnt_t,
                   int* __restrict__ base_t, int* __restrict__ cur_t,
                   const float* __restrict__ deg_t, float* __restrict__ dis_t) {
  if (blockIdx.x == 0) {
    scan_role(cnt_t, base_t, cur_t, deg_t, dis_t);
  } else {
    int eid = (blockIdx.x - 1) * 256 + threadIdx.x;
    int rr = bei[eid], c = bei[kEB + eid];
    float nrm = dis_b[rr] * bw[eid] * dis_b[c];
    int pos = atomicAdd(&cur_b[c], 1);
    csr_b[pos] = make_int2(rr, __float_as_int(nrm));
  }
}

// ================= L5: agg0 ∥ fill_t (round-striped) =================
__global__ __launch_bounds__(256)
void k_agg0_fillt(const u16* __restrict__ hb, const float* __restrict__ x,
                  const int2* __restrict__ csr_b, const int* __restrict__ base_b,
                  const float* __restrict__ dis_b, const float* __restrict__ bbias,
                  const float* __restrict__ gs, const float* __restrict__ bs,
                  u16* __restrict__ sb, const int* __restrict__ tei,
                  const float* __restrict__ tmpw, const float* __restrict__ dis_t,
                  int* __restrict__ cur_t, int2* __restrict__ csr_t) {
  int bid = blockIdx.x;
  int r = bid >> 8, idx = bid & 255;
  if (r % 3 == 1) {                           // 4 rounds x 256 = 1024 fill blocks
    int eid = ((r / 3) * 256 + idx) * 256 + threadIdx.x;
    int rr = tei[eid], c = tei[kET + eid];
    float nrm = dis_t[rr] * tmpw[eid] * dis_t[c];
    int pos = atomicAdd(&cur_t[c], 1);
    csr_t[pos] = make_int2(rr, __float_as_int(nrm));
  } else {                                    // 8 rounds x 256 = 2048 agg blocks
    int agg_ord = r - r / 3 - (r % 3 == 2 ? 1 : 0);
    agg_role<0>(hb, x, nullptr, csr_b, base_b, dis_b, bbias, gs, bs,
                nullptr, nullptr, sb, agg_ord * 256 + idx);
  }
}

// ============ bf16-MFMA GEMM (r15, 32 rows/block, 256 thr) ============
__global__ __launch_bounds__(256)
void k_gemm_mfma(const u16* __restrict__ Ab, const u16* __restrict__ pkW,
                 u16* __restrict__ Cb) {
  __shared__ __align__(16) u16 Atile[32 * 256];
  int tid = threadIdx.x;
  int w = tid >> 6, lane = tid & 63, low4 = lane & 15, hi = lane >> 4;
  int row0 = blockIdx.x * 32;

  const char* asrc = (const char*)(Ab + (size_t)row0 * 256);
#pragma unroll
  for (int i = 0; i < 4; ++i) {
    u32 d = (u32)(((i * 4 + w) * 64 + lane) * 16);
    GLOAD_LDS16(asrc + swz512(d), (char*)Atile + (i * 4 + w) * 1024);
  }

  floatx4 acc[2][4];
#pragma unroll
  for (int rt = 0; rt < 2; ++rt)
#pragma unroll
    for (int nn = 0; nn < 4; ++nn) acc[rt][nn] = (floatx4){0.f, 0.f, 0.f, 0.f};

  __syncthreads();

#pragma unroll
  for (int kt = 0; kt < 8; ++kt) {
    short8 bfr[4];
    const u16* pw = pkW + ((size_t)(kt * 16 + w * 4) * 64 + lane) * 8;
#pragma unroll
    for (int nn = 0; nn < 4; ++nn) bfr[nn] = *(const short8*)(pw + nn * 512);
    short8 afr[2];
#pragma unroll
    for (int rt = 0; rt < 2; ++rt) {
      u32 p = (u32)((rt * 16 + low4) * 512 + (kt * 32 + hi * 8) * 2);
      afr[rt] = *(const short8*)((const char*)Atile + swz512(p));
    }
#pragma unroll
    for (int rt = 0; rt < 2; ++rt)
#pragma unroll
      for (int nn = 0; nn < 4; ++nn)
        acc[rt][nn] = __builtin_amdgcn_mfma_f32_16x16x32_bf16(afr[rt], bfr[nn],
                                                              acc[rt][nn], 0, 0, 0);
  }
#pragma unroll
  for (int rt = 0; rt < 2; ++rt)
#pragma unroll
    for (int nn = 0; nn < 4; ++nn)
#pragma unroll
      for (int j = 0; j < 4; ++j) {
        int row = row0 + rt * 16 + hi * 4 + j;
        int col = w * 64 + nn * 16 + low4;
        Cb[(size_t)row * 256 + col] = (u16)bf16rn(acc[rt][nn][j]);
      }
}

// ================= L7: agg1 (final) =================
__global__ __launch_bounds__(256)
void k_agg1(const u16* __restrict__ h, const u16* __restrict__ sb,
            const float* __restrict__ x0, const int2* __restrict__ csr,
            const int* __restrict__ basep, const float* __restrict__ dis,
            const float* __restrict__ bias, const float* __restrict__ g1,
            const float* __restrict__ b1, const float* __restrict__ g2,
            const float* __restrict__ b2, float* __restrict__ outp) {
  agg_role<1>(h, sb, x0, csr, basep, dis, bias, g1, b1, g2, b2, outp, blockIdx.x);
}

extern "C" void kernel_launch(void* const* d_in, const int* in_sizes, int n_in,
                              void* d_out, int out_size, void* d_ws, size_t ws_size,
                              hipStream_t stream) {
  const float* x     = (const float*)d_in[0];
  const int*   bei   = (const int*)d_in[1];
  const float* bew   = (const float*)d_in[2];
  const int*   tei   = (const int*)d_in[3];
  const float* tattr = (const float*)d_in[4];
  const float* Wb    = (const float*)d_in[5];
  const float* bb    = (const float*)d_in[6];
  const float* Wt    = (const float*)d_in[7];
  const float* bt    = (const float*)d_in[8];
  const float* gs    = (const float*)d_in[9];
  const float* bs    = (const float*)d_in[10];
  const float* gt    = (const float*)d_in[11];
  const float* btn   = (const float*)d_in[12];
  const float* pw1   = (const float*)d_in[13];
  const float* pb1   = (const float*)d_in[14];
  const float* pg    = (const float*)d_in[15];
  const float* pbeta = (const float*)d_in[16];
  const float* pw2   = (const float*)d_in[17];
  const float* pb2   = (const float*)d_in[18];
  float* outp = (float*)d_out;

  size_t off = 0;
  auto alloc = [&](size_t bytes) -> void* {
    void* p = (char*)d_ws + off;
    off += (bytes + 255) & ~(size_t)255;
    return p;
  };
  float* deg_b = (float*)alloc(kN * 4);
  float* deg_t = (float*)alloc(kN * 4);
  int*   cnt_b = (int*)alloc(kN * 4);
  int*   cnt_t = (int*)alloc(kN * 4);       // deg_b..cnt_t contiguous: zero-role
  float* dis_b = (float*)alloc(kN * 4);
  float* dis_t = (float*)alloc(kN * 4);
  int*   base_b = (int*)alloc((kN + 1) * 4);
  int*   base_t = (int*)alloc((kN + 1) * 4);
  int*   cur_b  = (int*)alloc(kN * 4);
  int*   cur_t  = (int*)alloc(kN * 4);
  float* tmpw   = (float*)alloc(kET * 4);
  int2*  csr_b  = (int2*)alloc((size_t)kEB * 8);
  int2*  csr_t  = (int2*)alloc((size_t)kET * 8);
  u16*   pk1 = (u16*)alloc(32768 * 2);
  u16*   pkb = (u16*)alloc(65536 * 2);
  u16*   pkt = (u16*)alloc(65536 * 2);
  float4* pp = (float4*)alloc(256 * 16);
  u16*   xb  = (u16*)alloc((size_t)kN * HN * 2);
  u16*   hb  = (u16*)alloc((size_t)kN * HN * 2);
  u16*   sb  = (u16*)alloc((size_t)kN * HN * 2);
  (void)ws_size; (void)in_sizes; (void)n_in; (void)out_size;

  // L1: pack ∥ cvt ∥ zero(deg_b..cnt_t)
  k_prep_const<<<2753, 256, 0, stream>>>(pw1, Wb, Wt, pb1, pg, pbeta, pw2,
                                         pk1, pkb, pkt, pp, x, xb,
                                         (uint4*)deg_b);
  // L2: proj, gemm1, bold edge-prep (serial; the r16 fused version spilled)
  k_proj_mfma<<<kET / 128 / PROJ_TILES, 512, 0, stream>>>(tattr, pk1, pb1, pp,
                                                          pb2, tmpw);
  k_gemm_mfma<<<kN / 32, 256, 0, stream>>>(xb, pkb, hb);
  k_edge_prep_b<<<kEB / 256, 256, 0, stream>>>(bei + kEB, bew, deg_b, cnt_b);
  // L3: scan_b ∥ temporal edge-prep
  k_scanb_prept<<<1 + kET / 256, 256, 0, stream>>>(cnt_b, base_b, cur_b, deg_b,
                                                   dis_b, tei + kET, tmpw,
                                                   deg_t, cnt_t);
  // L4: fill_b ∥ scan_t
  k_fillb_scant<<<1 + kEB / 256, 256, 0, stream>>>(bei, bew, dis_b, cur_b, csr_b,
                                                   cnt_t, base_t, cur_t,
                                                   deg_t, dis_t);
  // L5: agg0 ∥ fill_t
  k_agg0_fillt<<<3072, 256, 0, stream>>>(hb, x, csr_b, base_b, dis_b, bb, gs, bs,
                                         sb, tei, tmpw, dis_t, cur_t, csr_t);
  // L6: gemm2
  k_gemm_mfma<<<kN / 32, 256, 0, stream>>>(sb, pkt, hb);
  // L7: agg1 + final LN
  k_agg1<<<kN / 8, 256, 0, stream>>>(hb, sb, x, csr_t, base_t, dis_t,
                                     bt, gt, btn, gs, bs, outp);
}

// Round 18
// 257.724 us; speedup vs baseline: 1.4241x; 1.0341x over previous
//
#include <hip/hip_runtime.h>

constexpr int kN  = 16384;
constexpr int kEB = 524288;
constexpr int kET = 262144;
constexpr int kTA = 107;
constexpr float kEps = 1e-5f;
#define HN 256

typedef __attribute__((ext_vector_type(8))) short short8;
typedef __attribute__((ext_vector_type(4))) float floatx4;
typedef unsigned short u16;
typedef unsigned int u32;

#define GLOAD_LDS16(gp, lp)                                                    \
  __builtin_amdgcn_global_load_lds(                                            \
      (const __attribute__((address_space(1))) u32*)(gp),                      \
      (__attribute__((address_space(3))) u32*)(lp), 16, 0, 0)

__device__ __forceinline__ u32 bf16rn(float f) {
  u32 u = __float_as_uint(f);
  return (u + 0x7FFFu + ((u >> 16) & 1u)) >> 16;
}
__device__ __forceinline__ u32 pack2(float a, float b) {
  return bf16rn(a) | (bf16rn(b) << 16);
}
__device__ __forceinline__ float bf2f(u32 v) {
  return __uint_as_float(v << 16);
}
__device__ __forceinline__ u32 cvtpk(float lo, float hi) {
  u32 r;
  asm("v_cvt_pk_bf16_f32 %0, %1, %2" : "=v"(r) : "v"(lo), "v"(hi));
  return r;
}
__device__ __forceinline__ void ub8(uint4 u, float* f) {
  f[0] = bf2f(u.x & 0xFFFF); f[1] = bf2f(u.x >> 16);
  f[2] = bf2f(u.y & 0xFFFF); f[3] = bf2f(u.y >> 16);
  f[4] = bf2f(u.z & 0xFFFF); f[5] = bf2f(u.z >> 16);
  f[6] = bf2f(u.w & 0xFFFF); f[7] = bf2f(u.w >> 16);
}
__device__ __forceinline__ u32 swz512(u32 b) { return b ^ (((b >> 9) & 7u) << 4); }

// ================= L1: pack weights ∥ cvt x ∥ zero deg/cnt =================
__global__ __launch_bounds__(256)
void k_prep_const(const float* __restrict__ w1, const float* __restrict__ Wb,
                  const float* __restrict__ Wt, const float* __restrict__ b1,
                  const float* __restrict__ pg, const float* __restrict__ pbeta,
                  const float* __restrict__ w2, u16* __restrict__ pk1,
                  u16* __restrict__ pkb, u16* __restrict__ pkt,
                  float4* __restrict__ pp, const float* __restrict__ x,
                  u16* __restrict__ xb, uint4* __restrict__ zero4) {
  int bid = blockIdx.x, tid = threadIdx.x;
  if (bid < 641) {
    int idx = bid * 256 + tid;
    if (idx < 32768) {                       // w1: K=128 padded from 107
      int e = idx & 7, lane = (idx >> 3) & 63, ct = (idx >> 9) & 15, kk = idx >> 13;
      int k = kk * 32 + (lane >> 4) * 8 + e, col = ct * 16 + (lane & 15);
      pk1[idx] = (u16)(k < kTA ? bf16rn(w1[(size_t)k * 256 + col]) : 0);
    } else if (idx < 163840) {
      int j = idx - 32768;
      const float* W = (j < 65536) ? Wb : Wt;
      u16* pk = (j < 65536) ? pkb : pkt;
      int t = j & 65535;
      int e = t & 7, lane = (t >> 3) & 63, ct = (t >> 9) & 15, kt = t >> 13;
      int k = kt * 32 + (lane >> 4) * 8 + e, col = ct * 16 + (lane & 15);
      pk[t] = (u16)bf16rn(W[(size_t)k * 256 + col]);
    } else if (idx < 163840 + 256) {
      int col = idx - 163840;
      pp[col] = make_float4(b1[col], pg[col], pbeta[col], w2[col]);
    }
  } else if (bid < 641 + 2048) {
    size_t i = (size_t)((bid - 641) * 256 + tid) * 8;
    float4 a = *(const float4*)(x + i);
    float4 b = *(const float4*)(x + i + 4);
    *(uint4*)(xb + i) = make_uint4(pack2(a.x, a.y), pack2(a.z, a.w),
                                   pack2(b.x, b.y), pack2(b.z, b.w));
  } else {
    zero4[(bid - 2689) * 256 + tid] = make_uint4(0, 0, 0, 0);
  }
}

// ============ proj: persistent B, 512-thr, pipelined tiles (r15) ============
#define PROJ_TILES 4
__global__ __launch_bounds__(512)
void k_proj_mfma(const float* __restrict__ attr, const u16* __restrict__ pk1,
                 const float* __restrict__ b1, const float4* __restrict__ pp,
                 const float* __restrict__ b2, float* __restrict__ temp_w) {
  __shared__ __align__(16) u16 Btile[32768];   // 64 KB = whole packed w1
  int tid = threadIdx.x;
  int w = tid >> 6, lane = tid & 63, low4 = lane & 15, hi = lane >> 4;

#pragma unroll
  for (int it = 0; it < 8; ++it) {
    int chunk = it * 512 + tid;
    GLOAD_LDS16((const char*)pk1 + (size_t)chunk * 16,
                (char*)Btile + (it * 512 + w * 64) * 16);
  }

  auto buildA = [&](int t, short8* a) {
    int e0 = (blockIdx.x * PROJ_TILES + t) * 128 + w * 16;
    const float* rowp = attr + (size_t)(e0 + low4) * kTA;
#pragma unroll
    for (int kk = 0; kk < 4; ++kk) {
      int kb = kk * 32 + hi * 8;
      float v[8];
#pragma unroll
      for (int e = 0; e < 8; ++e)
        v[e] = (kk < 3 || kb + e < kTA) ? rowp[kb + e] : 0.f;
      union { short8 s8; uint4 u4; } fr;
      fr.u4 = make_uint4(cvtpk(v[0], v[1]), cvtpk(v[2], v[3]),
                         cvtpk(v[4], v[5]), cvtpk(v[6], v[7]));
      a[kk] = fr.s8;
    }
  };

  short8 a_cur[4];
  buildA(0, a_cur);
  float b2s = b2[0];

  __syncthreads();

#pragma unroll
  for (int t = 0; t < PROJ_TILES; ++t) {
    int e0 = (blockIdx.x * PROJ_TILES + t) * 128 + w * 16;
    short8 a_next[4];
    if (t + 1 < PROJ_TILES) buildA(t + 1, a_next);

    u32 hvpk[16][2];
    float s1[4] = {0.f, 0.f, 0.f, 0.f}, s2[4] = {0.f, 0.f, 0.f, 0.f};
#pragma unroll
    for (int nn = 0; nn < 16; ++nn) {
      floatx4 acc = (floatx4){0.f, 0.f, 0.f, 0.f};
#pragma unroll
      for (int kk = 0; kk < 4; ++kk) {
        short8 bfr = *(const short8*)(Btile + ((size_t)(kk * 16 + nn) * 64 + lane) * 8);
        acc = __builtin_amdgcn_mfma_f32_16x16x32_bf16(a_cur[kk], bfr, acc, 0, 0, 0);
      }
      float b1v = b1[nn * 16 + low4];
      float h0 = acc[0] + b1v, h1 = acc[1] + b1v, h2 = acc[2] + b1v, h3 = acc[3] + b1v;
      s1[0] += h0; s2[0] += h0 * h0;
      s1[1] += h1; s2[1] += h1 * h1;
      s1[2] += h2; s2[2] += h2 * h2;
      s1[3] += h3; s2[3] += h3 * h3;
      hvpk[nn][0] = cvtpk(h0, h1);
      hvpk[nn][1] = cvtpk(h2, h3);
    }

    float mean[4], inv[4];
#pragma unroll
    for (int j = 0; j < 4; ++j) {
#pragma unroll
      for (int m = 1; m < 16; m <<= 1) {
        s1[j] += __shfl_xor(s1[j], m, 64);
        s2[j] += __shfl_xor(s2[j], m, 64);
      }
      mean[j] = s1[j] * (1.f / 256);
      inv[j] = rsqrtf(s2[j] * (1.f / 256) - mean[j] * mean[j] + kEps);
    }

    float d[4] = {0.f, 0.f, 0.f, 0.f};
#pragma unroll
    for (int nn = 0; nn < 16; ++nn) {
      float4 p = pp[nn * 16 + low4];
      float h0 = bf2f(hvpk[nn][0] & 0xFFFF);
      float h1 = bf2f(hvpk[nn][0] >> 16);
      float h2 = bf2f(hvpk[nn][1] & 0xFFFF);
      float h3 = bf2f(hvpk[nn][1] >> 16);
      d[0] += fmaxf((h0 - mean[0]) * inv[0] * p.y + p.z, 0.f) * p.w;
      d[1] += fmaxf((h1 - mean[1]) * inv[1] * p.y + p.z, 0.f) * p.w;
      d[2] += fmaxf((h2 - mean[2]) * inv[2] * p.y + p.z, 0.f) * p.w;
      d[3] += fmaxf((h3 - mean[3]) * inv[3] * p.y + p.z, 0.f) * p.w;
    }
#pragma unroll
    for (int j = 0; j < 4; ++j) {
#pragma unroll
      for (int m = 1; m < 16; m <<= 1) d[j] += __shfl_xor(d[j], m, 64);
      if (low4 == 0) temp_w[e0 + hi * 4 + j] = d[j] + b2s;
    }
#pragma unroll
    for (int kk = 0; kk < 4; ++kk) a_cur[kk] = a_next[kk];
  }
}

// ============ gemm role (r15 body, 32 rows, 256 thr slice) ============
__device__ __forceinline__
void gemm_role(u16* Atile, const u16* __restrict__ Ab,
               const u16* __restrict__ pkW, u16* __restrict__ Cb, int gid) {
  int tid = threadIdx.x;
  int w = tid >> 6, lane = tid & 63, low4 = lane & 15, hi = lane >> 4;
  int row0 = gid * 32;

  const char* asrc = (const char*)(Ab + (size_t)row0 * 256);
#pragma unroll
  for (int i = 0; i < 4; ++i) {
    u32 d = (u32)(((i * 4 + w) * 64 + lane) * 16);
    GLOAD_LDS16(asrc + swz512(d), (char*)Atile + (i * 4 + w) * 1024);
  }

  floatx4 acc[2][4];
#pragma unroll
  for (int rt = 0; rt < 2; ++rt)
#pragma unroll
    for (int nn = 0; nn < 4; ++nn) acc[rt][nn] = (floatx4){0.f, 0.f, 0.f, 0.f};

  __syncthreads();

#pragma unroll
  for (int kt = 0; kt < 8; ++kt) {
    short8 bfr[4];
    const u16* pw = pkW + ((size_t)(kt * 16 + w * 4) * 64 + lane) * 8;
#pragma unroll
    for (int nn = 0; nn < 4; ++nn) bfr[nn] = *(const short8*)(pw + nn * 512);
    short8 afr[2];
#pragma unroll
    for (int rt = 0; rt < 2; ++rt) {
      u32 p = (u32)((rt * 16 + low4) * 512 + (kt * 32 + hi * 8) * 2);
      afr[rt] = *(const short8*)((const char*)Atile + swz512(p));
    }
#pragma unroll
    for (int rt = 0; rt < 2; ++rt)
#pragma unroll
      for (int nn = 0; nn < 4; ++nn)
        acc[rt][nn] = __builtin_amdgcn_mfma_f32_16x16x32_bf16(afr[rt], bfr[nn],
                                                              acc[rt][nn], 0, 0, 0);
  }
#pragma unroll
  for (int rt = 0; rt < 2; ++rt)
#pragma unroll
    for (int nn = 0; nn < 4; ++nn)
#pragma unroll
      for (int j = 0; j < 4; ++j) {
        int row = row0 + rt * 16 + hi * 4 + j;
        int col = w * 64 + nn * 16 + low4;
        Cb[(size_t)row * 256 + col] = (u16)bf16rn(acc[rt][nn][j]);
      }
}

// ============ L2b: gemm1 ∥ bold edge-prep (round-striped, both low-VGPR) ====
__global__ __launch_bounds__(256)
void k_gemm1_prepb(const u16* __restrict__ xb, const u16* __restrict__ pkb,
                   u16* __restrict__ hb, const int* __restrict__ bcol,
                   const float* __restrict__ bw, float* __restrict__ deg_b,
                   int* __restrict__ cnt_b) {
  __shared__ __align__(16) u16 Atile[32 * 256];
  int bid = blockIdx.x;
  int r = bid >> 8, idx = bid & 255;
  if (r < 2) {                                // 512 gemm blocks
    gemm_role(Atile, xb, pkb, hb, r * 256 + idx);
  } else {                                    // 2048 prep blocks
    int e = ((r - 2) * 256 + idx) * 256 + threadIdx.x;
    int c = bcol[e];
    atomicAdd(&deg_b[c], bw[e]);
    atomicAdd(&cnt_b[c], 1);
  }
}

// ============ scan role (256 threads) ============
__device__ __forceinline__
void scan_role(const int* __restrict__ cnt, int* __restrict__ base,
               int* __restrict__ cur, const float* __restrict__ deg,
               float* __restrict__ dis) {
  __shared__ int part[256];
  int tid = threadIdx.x;
  int per = kN >> 8;
  int i0 = tid * per;
  int s = 0;
  for (int k = 0; k < per; ++k) s += cnt[i0 + k];
  part[tid] = s;
  __syncthreads();
  for (int off = 1; off < 256; off <<= 1) {
    int v = (tid >= off) ? part[tid - off] : 0;
    __syncthreads();
    part[tid] += v;
    __syncthreads();
  }
  int run = (tid == 0) ? 0 : part[tid - 1];
  for (int k = 0; k < per; ++k) {
    base[i0 + k] = run; cur[i0 + k] = run; run += cnt[i0 + k];
    float d = deg[i0 + k] + 1.0f;
    dis[i0 + k] = (d > 0.f) ? rsqrtf(d) : 0.f;
  }
  if (tid == 255) base[kN] = run;
}

// ============ agg role: 32 lanes/node, 8 nodes per 256-thread block ============
template <int FINAL>
__device__ __forceinline__
void agg_role(const u16* __restrict__ h, const void* __restrict__ residv,
              const float* __restrict__ x0, const int2* __restrict__ csr,
              const int* __restrict__ basep, const float* __restrict__ dis,
              const float* __restrict__ bias, const float* __restrict__ g1,
              const float* __restrict__ b1, const float* __restrict__ g2,
              const float* __restrict__ b2, void* __restrict__ outv, int aid) {
  int tid = threadIdx.x;
  int sub = tid >> 5, lane = tid & 31;
  int node = aid * 8 + sub;
  int c = lane * 8;
  const u16* hcol = h + c;
  float di = dis[node];
  float sl = di * di;
  float acc[8];
  {
    uint4 u = *(const uint4*)(hcol + (size_t)node * HN);
    float f[8]; ub8(u, f);
#pragma unroll
    for (int i = 0; i < 8; ++i) acc[i] = f[i] * sl;
  }
  int e0 = basep[node], e1 = basep[node + 1];
  int k = e0;
  for (; k + 4 <= e1; k += 4) {
    int2 p0 = csr[k], p1 = csr[k + 1], p2 = csr[k + 2], p3 = csr[k + 3];
    uint4 u0 = *(const uint4*)(hcol + (size_t)p0.x * HN);
    uint4 u1 = *(const uint4*)(hcol + (size_t)p1.x * HN);
    uint4 u2 = *(const uint4*)(hcol + (size_t)p2.x * HN);
    uint4 u3 = *(const uint4*)(hcol + (size_t)p3.x * HN);
    float n0 = __int_as_float(p0.y), n1 = __int_as_float(p1.y);
    float n2 = __int_as_float(p2.y), n3 = __int_as_float(p3.y);
    float f0[8], f1[8], f2[8], f3[8];
    ub8(u0, f0); ub8(u1, f1); ub8(u2, f2); ub8(u3, f3);
#pragma unroll
    for (int i = 0; i < 8; ++i)
      acc[i] += n0 * f0[i] + n1 * f1[i] + n2 * f2[i] + n3 * f3[i];
  }
  for (; k < e1; ++k) {
    int2 p = csr[k];
    uint4 u = *(const uint4*)(hcol + (size_t)p.x * HN);
    float nf = __int_as_float(p.y);
    float f[8]; ub8(u, f);
#pragma unroll
    for (int i = 0; i < 8; ++i) acc[i] += nf * f[i];
  }
  float v[8];
  {
    float4 b0 = *(const float4*)(bias + c);
    float4 b4 = *(const float4*)(bias + c + 4);
    float bb[8] = {b0.x, b0.y, b0.z, b0.w, b4.x, b4.y, b4.z, b4.w};
    float rr[8];
    if (!FINAL) {
      const float* rp = (const float*)residv + (size_t)node * HN + c;
      float4 r0 = *(const float4*)rp;
      float4 r4 = *(const float4*)(rp + 4);
      rr[0] = r0.x; rr[1] = r0.y; rr[2] = r0.z; rr[3] = r0.w;
      rr[4] = r4.x; rr[5] = r4.y; rr[6] = r4.z; rr[7] = r4.w;
    } else {
      uint4 u = *(const uint4*)((const u16*)residv + (size_t)node * HN + c);
      ub8(u, rr);
    }
#pragma unroll
    for (int i = 0; i < 8; ++i) v[i] = acc[i] + bb[i] + rr[i];
  }
  float s1 = 0.f, s2 = 0.f;
#pragma unroll
  for (int i = 0; i < 8; ++i) { s1 += v[i]; s2 += v[i] * v[i]; }
#pragma unroll
  for (int m = 1; m < 32; m <<= 1) {
    s1 += __shfl_xor(s1, m, 64);
    s2 += __shfl_xor(s2, m, 64);
  }
  float mean = s1 * (1.f / HN);
  float inv = rsqrtf(s2 * (1.f / HN) - mean * mean + kEps);
  float4 ga = *(const float4*)(g1 + c);
  float4 gb = *(const float4*)(g1 + c + 4);
  float4 ba = *(const float4*)(b1 + c);
  float4 bbv = *(const float4*)(b1 + c + 4);
  float gg[8] = {ga.x, ga.y, ga.z, ga.w, gb.x, gb.y, gb.z, gb.w};
  float bt[8] = {ba.x, ba.y, ba.z, ba.w, bbv.x, bbv.y, bbv.z, bbv.w};
  float y[8];
#pragma unroll
  for (int i = 0; i < 8; ++i)
    y[i] = fmaxf((v[i] - mean) * inv * gg[i] + bt[i], 0.f);
  if (!FINAL) {
    uint4 o = make_uint4(cvtpk(y[0], y[1]), cvtpk(y[2], y[3]),
                         cvtpk(y[4], y[5]), cvtpk(y[6], y[7]));
    *(uint4*)((u16*)outv + (size_t)node * HN + c) = o;
  } else {
    const float* xp = x0 + (size_t)node * HN + c;
    float4 x0v = *(const float4*)xp;
    float4 x4v = *(const float4*)(xp + 4);
    float xx[8] = {x0v.x, x0v.y, x0v.z, x0v.w, x4v.x, x4v.y, x4v.z, x4v.w};
    float z[8];
    float t1 = 0.f, t2 = 0.f;
#pragma unroll
    for (int i = 0; i < 8; ++i) {
      z[i] = y[i] + xx[i];
      t1 += z[i]; t2 += z[i] * z[i];
    }
#pragma unroll
    for (int m = 1; m < 32; m <<= 1) {
      t1 += __shfl_xor(t1, m, 64);
      t2 += __shfl_xor(t2, m, 64);
    }
    float m2 = t1 * (1.f / HN);
    float i2 = rsqrtf(t2 * (1.f / HN) - m2 * m2 + kEps);
    float4 Ga = *(const float4*)(g2 + c);
    float4 Gb = *(const float4*)(g2 + c + 4);
    float4 Ba = *(const float4*)(b2 + c);
    float4 Bb = *(const float4*)(b2 + c + 4);
    float G[8] = {Ga.x, Ga.y, Ga.z, Ga.w, Gb.x, Gb.y, Gb.z, Gb.w};
    float B[8] = {Ba.x, Ba.y, Ba.z, Ba.w, Bb.x, Bb.y, Bb.z, Bb.w};
    float* op = (float*)outv + (size_t)node * HN + c;
    *(float4*)op = make_float4((z[0] - m2) * i2 * G[0] + B[0],
                               (z[1] - m2) * i2 * G[1] + B[1],
                               (z[2] - m2) * i2 * G[2] + B[2],
                               (z[3] - m2) * i2 * G[3] + B[3]);
    *(float4*)(op + 4) = make_float4((z[4] - m2) * i2 * G[4] + B[4],
                                     (z[5] - m2) * i2 * G[5] + B[5],
                                     (z[6] - m2) * i2 * G[6] + B[6],
                                     (z[7] - m2) * i2 * G[7] + B[7]);
  }
}

// ================= L3: scan_b ∥ temporal edge-prep =================
__global__ __launch_bounds__(256)
void k_scanb_prept(const int* __restrict__ cnt_b, int* __restrict__ base_b,
                   int* __restrict__ cur_b, const float* __restrict__ deg_b,
                   float* __restrict__ dis_b, const int* __restrict__ tcol,
                   const float* __restrict__ tmpw, float* __restrict__ deg_t,
                   int* __restrict__ cnt_t) {
  if (blockIdx.x == 0) {
    scan_role(cnt_b, base_b, cur_b, deg_b, dis_b);
  } else {
    int eid = (blockIdx.x - 1) * 256 + threadIdx.x;
    int c = tcol[eid];
    atomicAdd(&deg_t[c], tmpw[eid]);
    atomicAdd(&cnt_t[c], 1);
  }
}

// ================= L4: fill_b ∥ scan_t =================
__global__ __launch_bounds__(256)
void k_fillb_scant(const int* __restrict__ bei, const float* __restrict__ bw,
                   const float* __restrict__ dis_b, int* __restrict__ cur_b,
                   int2* __restrict__ csr_b, const int* __restrict__ cnt_t,
                   int* __restrict__ base_t, int* __restrict__ cur_t,
                   const float* __restrict__ deg_t, float* __restrict__ dis_t) {
  if (blockIdx.x == 0) {
    scan_role(cnt_t, base_t, cur_t, deg_t, dis_t);
  } else {
    int eid = (blockIdx.x - 1) * 256 + threadIdx.x;
    int rr = bei[eid], c = bei[kEB + eid];
    float nrm = dis_b[rr] * bw[eid] * dis_b[c];
    int pos = atomicAdd(&cur_b[c], 1);
    csr_b[pos] = make_int2(rr, __float_as_int(nrm));
  }
}

// ================= L5: agg0 ∥ fill_t (round-striped) =================
__global__ __launch_bounds__(256)
void k_agg0_fillt(const u16* __restrict__ hb, const float* __restrict__ x,
                  const int2* __restrict__ csr_b, const int* __restrict__ base_b,
                  const float* __restrict__ dis_b, const float* __restrict__ bbias,
                  const float* __restrict__ gs, const float* __restrict__ bs,
                  u16* __restrict__ sb, const int* __restrict__ tei,
                  const float* __restrict__ tmpw, const float* __restrict__ dis_t,
                  int* __restrict__ cur_t, int2* __restrict__ csr_t) {
  int bid = blockIdx.x;
  int r = bid >> 8, idx = bid & 255;
  if (r % 3 == 1) {                           // 4 rounds x 256 = 1024 fill blocks
    int eid = ((r / 3) * 256 + idx) * 256 + threadIdx.x;
    int rr = tei[eid], c = tei[kET + eid];
    float nrm = dis_t[rr] * tmpw[eid] * dis_t[c];
    int pos = atomicAdd(&cur_t[c], 1);
    csr_t[pos] = make_int2(rr, __float_as_int(nrm));
  } else {                                    // 8 rounds x 256 = 2048 agg blocks
    int agg_ord = r - r / 3 - (r % 3 == 2 ? 1 : 0);
    agg_role<0>(hb, x, nullptr, csr_b, base_b, dis_b, bbias, gs, bs,
                nullptr, nullptr, sb, agg_ord * 256 + idx);
  }
}

// ============ L6: gemm2 (standalone) ============
__global__ __launch_bounds__(256)
void k_gemm_mfma(const u16* __restrict__ Ab, const u16* __restrict__ pkW,
                 u16* __restrict__ Cb) {
  __shared__ __align__(16) u16 Atile[32 * 256];
  gemm_role(Atile, Ab, pkW, Cb, blockIdx.x);
}

// ================= L7: agg1 (final) =================
__global__ __launch_bounds__(256)
void k_agg1(const u16* __restrict__ h, const u16* __restrict__ sb,
            const float* __restrict__ x0, const int2* __restrict__ csr,
            const int* __restrict__ basep, const float* __restrict__ dis,
            const float* __restrict__ bias, const float* __restrict__ g1,
            const float* __restrict__ b1, const float* __restrict__ g2,
            const float* __restrict__ b2, float* __restrict__ outp) {
  agg_role<1>(h, sb, x0, csr, basep, dis, bias, g1, b1, g2, b2, outp, blockIdx.x);
}

extern "C" void kernel_launch(void* const* d_in, const int* in_sizes, int n_in,
                              void* d_out, int out_size, void* d_ws, size_t ws_size,
                              hipStream_t stream) {
  const float* x     = (const float*)d_in[0];
  const int*   bei   = (const int*)d_in[1];
  const float* bew   = (const float*)d_in[2];
  const int*   tei   = (const int*)d_in[3];
  const float* tattr = (const float*)d_in[4];
  const float* Wb    = (const float*)d_in[5];
  const float* bb    = (const float*)d_in[6];
  const float* Wt    = (const float*)d_in[7];
  const float* bt    = (const float*)d_in[8];
  const float* gs    = (const float*)d_in[9];
  const float* bs    = (const float*)d_in[10];
  const float* gt    = (const float*)d_in[11];
  const float* btn   = (const float*)d_in[12];
  const float* pw1   = (const float*)d_in[13];
  const float* pb1   = (const float*)d_in[14];
  const float* pg    = (const float*)d_in[15];
  const float* pbeta = (const float*)d_in[16];
  const float* pw2   = (const float*)d_in[17];
  const float* pb2   = (const float*)d_in[18];
  float* outp = (float*)d_out;

  size_t off = 0;
  auto alloc = [&](size_t bytes) -> void* {
    void* p = (char*)d_ws + off;
    off += (bytes + 255) & ~(size_t)255;
    return p;
  };
  float* deg_b = (float*)alloc(kN * 4);
  float* deg_t = (float*)alloc(kN * 4);
  int*   cnt_b = (int*)alloc(kN * 4);
  int*   cnt_t = (int*)alloc(kN * 4);       // deg_b..cnt_t contiguous: zero-role
  float* dis_b = (float*)alloc(kN * 4);
  float* dis_t = (float*)alloc(kN * 4);
  int*   base_b = (int*)alloc((kN + 1) * 4);
  int*   base_t = (int*)alloc((kN + 1) * 4);
  int*   cur_b  = (int*)alloc(kN * 4);
  int*   cur_t  = (int*)alloc(kN * 4);
  float* tmpw   = (float*)alloc(kET * 4);
  int2*  csr_b  = (int2*)alloc((size_t)kEB * 8);
  int2*  csr_t  = (int2*)alloc((size_t)kET * 8);
  u16*   pk1 = (u16*)alloc(32768 * 2);
  u16*   pkb = (u16*)alloc(65536 * 2);
  u16*   pkt = (u16*)alloc(65536 * 2);
  float4* pp = (float4*)alloc(256 * 16);
  u16*   xb  = (u16*)alloc((size_t)kN * HN * 2);
  u16*   hb  = (u16*)alloc((size_t)kN * HN * 2);
  u16*   sb  = (u16*)alloc((size_t)kN * HN * 2);
  (void)ws_size; (void)in_sizes; (void)n_in; (void)out_size;

  // L1: pack ∥ cvt ∥ zero(deg_b..cnt_t)
  k_prep_const<<<2753, 256, 0, stream>>>(pw1, Wb, Wt, pb1, pg, pbeta, pw2,
                                         pk1, pkb, pkt, pp, x, xb,
                                         (uint4*)deg_b);
  // L2a: proj (standalone — fusing it spills, r16)
  k_proj_mfma<<<kET / 128 / PROJ_TILES, 512, 0, stream>>>(tattr, pk1, pb1, pp,
                                                          pb2, tmpw);
  // L2b: gemm1 ∥ bold edge-prep (both low-VGPR -> safe pairing)
  k_gemm1_prepb<<<2560, 256, 0, stream>>>(xb, pkb, hb, bei + kEB, bew,
                                          deg_b, cnt_b);
  // L3: scan_b ∥ temporal edge-prep
  k_scanb_prept<<<1 + kET / 256, 256, 0, stream>>>(cnt_b, base_b, cur_b, deg_b,
                                                   dis_b, tei + kET, tmpw,
                                                   deg_t, cnt_t);
  // L4: fill_b ∥ scan_t
  k_fillb_scant<<<1 + kEB / 256, 256, 0, stream>>>(bei, bew, dis_b, cur_b, csr_b,
                                                   cnt_t, base_t, cur_t,
                                                   deg_t, dis_t);
  // L5: agg0 ∥ fill_t
  k_agg0_fillt<<<3072, 256, 0, stream>>>(hb, x, csr_b, base_b, dis_b, bb, gs, bs,
                                         sb, tei, tmpw, dis_t, cur_t, csr_t);
  // L6: gemm2
  k_gemm_mfma<<<kN / 32, 256, 0, stream>>>(sb, pkt, hb);
  // L7: agg1 + final LN
  k_agg1<<<kN / 8, 256, 0, stream>>>(hb, sb, x, csr_t, base_t, dis_t,
                                     bt, gt, btn, gs, bs, outp);
}

// Round 19
// 256.116 us; speedup vs baseline: 1.4331x; 1.0063x over previous
//
#include <hip/hip_runtime.h>

constexpr int kN  = 16384;
constexpr int kEB = 524288;
constexpr int kET = 262144;
constexpr int kTA = 107;
constexpr float kEps = 1e-5f;
#define HN 256

typedef __attribute__((ext_vector_type(8))) short short8;
typedef __attribute__((ext_vector_type(4))) float floatx4;
typedef unsigned short u16;
typedef unsigned int u32;

#define GLOAD_LDS16(gp, lp)                                                    \
  __builtin_amdgcn_global_load_lds(                                            \
      (const __attribute__((address_space(1))) u32*)(gp),                      \
      (__attribute__((address_space(3))) u32*)(lp), 16, 0, 0)

__device__ __forceinline__ u32 bf16rn(float f) {
  u32 u = __float_as_uint(f);
  return (u + 0x7FFFu + ((u >> 16) & 1u)) >> 16;
}
__device__ __forceinline__ u32 pack2(float a, float b) {
  return bf16rn(a) | (bf16rn(b) << 16);
}
__device__ __forceinline__ float bf2f(u32 v) {
  return __uint_as_float(v << 16);
}
__device__ __forceinline__ u32 cvtpk(float lo, float hi) {
  u32 r;
  asm("v_cvt_pk_bf16_f32 %0, %1, %2" : "=v"(r) : "v"(lo), "v"(hi));
  return r;
}
__device__ __forceinline__ void ub8(uint4 u, float* f) {
  f[0] = bf2f(u.x & 0xFFFF); f[1] = bf2f(u.x >> 16);
  f[2] = bf2f(u.y & 0xFFFF); f[3] = bf2f(u.y >> 16);
  f[4] = bf2f(u.z & 0xFFFF); f[5] = bf2f(u.z >> 16);
  f[6] = bf2f(u.w & 0xFFFF); f[7] = bf2f(u.w >> 16);
}
__device__ __forceinline__ u32 swz512(u32 b) { return b ^ (((b >> 9) & 7u) << 4); }

// ================= L1: pack weights ∥ cvt x ∥ zero deg/cnt =================
__global__ __launch_bounds__(256)
void k_prep_const(const float* __restrict__ w1, const float* __restrict__ Wb,
                  const float* __restrict__ Wt, const float* __restrict__ b1,
                  const float* __restrict__ pg, const float* __restrict__ pbeta,
                  const float* __restrict__ w2, u16* __restrict__ pk1,
                  u16* __restrict__ pkb, u16* __restrict__ pkt,
                  float4* __restrict__ pp, const float* __restrict__ x,
                  u16* __restrict__ xb, uint4* __restrict__ zero4) {
  int bid = blockIdx.x, tid = threadIdx.x;
  if (bid < 641) {
    int idx = bid * 256 + tid;
    if (idx < 32768) {                       // w1: K=128 padded from 107
      int e = idx & 7, lane = (idx >> 3) & 63, ct = (idx >> 9) & 15, kk = idx >> 13;
      int k = kk * 32 + (lane >> 4) * 8 + e, col = ct * 16 + (lane & 15);
      pk1[idx] = (u16)(k < kTA ? bf16rn(w1[(size_t)k * 256 + col]) : 0);
    } else if (idx < 163840) {
      int j = idx - 32768;
      const float* W = (j < 65536) ? Wb : Wt;
      u16* pk = (j < 65536) ? pkb : pkt;
      int t = j & 65535;
      int e = t & 7, lane = (t >> 3) & 63, ct = (t >> 9) & 15, kt = t >> 13;
      int k = kt * 32 + (lane >> 4) * 8 + e, col = ct * 16 + (lane & 15);
      pk[t] = (u16)bf16rn(W[(size_t)k * 256 + col]);
    } else if (idx < 163840 + 256) {
      int col = idx - 163840;
      pp[col] = make_float4(b1[col], pg[col], pbeta[col], w2[col]);
    }
  } else if (bid < 641 + 2048) {
    size_t i = (size_t)((bid - 641) * 256 + tid) * 8;
    float4 a = *(const float4*)(x + i);
    float4 b = *(const float4*)(x + i + 4);
    *(uint4*)(xb + i) = make_uint4(pack2(a.x, a.y), pack2(a.z, a.w),
                                   pack2(b.x, b.y), pack2(b.z, b.w));
  } else {
    zero4[(bid - 2689) * 256 + tid] = make_uint4(0, 0, 0, 0);
  }
}

// ============ L2a: proj ∥ bold edge-prep (512 threads, round-striped) ======
// proj role = r15 body (80 VGPR); prep role is trivial (~16 VGPR) -> merged
// allocation stays at proj's level, unlike r16's proj+gemm merge (128, spill).
#define PROJ_TILES 4
__global__ __launch_bounds__(512)
void k_proj_prepb(const float* __restrict__ attr, const u16* __restrict__ pk1,
                  const float* __restrict__ b1, const float4* __restrict__ pp,
                  const float* __restrict__ b2, float* __restrict__ temp_w,
                  const int* __restrict__ bcol, const float* __restrict__ bw,
                  float* __restrict__ deg_b, int* __restrict__ cnt_b) {
  __shared__ __align__(16) u16 Btile[32768];   // 64 KB = whole packed w1
  int bid = blockIdx.x, tid = threadIdx.x;
  int r = bid >> 8, idx = bid & 255;

  if (r == 1 || r >= 3) {                     // prep rounds {1,3,4,5}: 1024 blocks
    int prepord = (r == 1) ? 0 : r - 2;
    int e = (prepord * 256 + idx) * 512 + tid;
    int c = bcol[e];
    atomicAdd(&deg_b[c], bw[e]);
    atomicAdd(&cnt_b[c], 1);
    return;
  }
  int projid = idx + (r == 2 ? 256 : 0);      // proj rounds {0,2}: 512 blocks

  int w = tid >> 6, lane = tid & 63, low4 = lane & 15, hi = lane >> 4;

#pragma unroll
  for (int it = 0; it < 8; ++it) {
    int chunk = it * 512 + tid;
    GLOAD_LDS16((const char*)pk1 + (size_t)chunk * 16,
                (char*)Btile + (it * 512 + w * 64) * 16);
  }

  auto buildA = [&](int t, short8* a) {
    int e0 = (projid * PROJ_TILES + t) * 128 + w * 16;
    const float* rowp = attr + (size_t)(e0 + low4) * kTA;
#pragma unroll
    for (int kk = 0; kk < 4; ++kk) {
      int kb = kk * 32 + hi * 8;
      float v[8];
#pragma unroll
      for (int e = 0; e < 8; ++e)
        v[e] = (kk < 3 || kb + e < kTA) ? rowp[kb + e] : 0.f;
      union { short8 s8; uint4 u4; } fr;
      fr.u4 = make_uint4(cvtpk(v[0], v[1]), cvtpk(v[2], v[3]),
                         cvtpk(v[4], v[5]), cvtpk(v[6], v[7]));
      a[kk] = fr.s8;
    }
  };

  short8 a_cur[4];
  buildA(0, a_cur);
  float b2s = b2[0];

  __syncthreads();

#pragma unroll
  for (int t = 0; t < PROJ_TILES; ++t) {
    int e0 = (projid * PROJ_TILES + t) * 128 + w * 16;
    short8 a_next[4];
    if (t + 1 < PROJ_TILES) buildA(t + 1, a_next);

    u32 hvpk[16][2];
    float s1[4] = {0.f, 0.f, 0.f, 0.f}, s2[4] = {0.f, 0.f, 0.f, 0.f};
#pragma unroll
    for (int nn = 0; nn < 16; ++nn) {
      floatx4 acc = (floatx4){0.f, 0.f, 0.f, 0.f};
#pragma unroll
      for (int kk = 0; kk < 4; ++kk) {
        short8 bfr = *(const short8*)(Btile + ((size_t)(kk * 16 + nn) * 64 + lane) * 8);
        acc = __builtin_amdgcn_mfma_f32_16x16x32_bf16(a_cur[kk], bfr, acc, 0, 0, 0);
      }
      float b1v = b1[nn * 16 + low4];
      float h0 = acc[0] + b1v, h1 = acc[1] + b1v, h2 = acc[2] + b1v, h3 = acc[3] + b1v;
      s1[0] += h0; s2[0] += h0 * h0;
      s1[1] += h1; s2[1] += h1 * h1;
      s1[2] += h2; s2[2] += h2 * h2;
      s1[3] += h3; s2[3] += h3 * h3;
      hvpk[nn][0] = cvtpk(h0, h1);
      hvpk[nn][1] = cvtpk(h2, h3);
    }

    float mean[4], inv[4];
#pragma unroll
    for (int j = 0; j < 4; ++j) {
#pragma unroll
      for (int m = 1; m < 16; m <<= 1) {
        s1[j] += __shfl_xor(s1[j], m, 64);
        s2[j] += __shfl_xor(s2[j], m, 64);
      }
      mean[j] = s1[j] * (1.f / 256);
      inv[j] = rsqrtf(s2[j] * (1.f / 256) - mean[j] * mean[j] + kEps);
    }

    float d[4] = {0.f, 0.f, 0.f, 0.f};
#pragma unroll
    for (int nn = 0; nn < 16; ++nn) {
      float4 p = pp[nn * 16 + low4];
      float h0 = bf2f(hvpk[nn][0] & 0xFFFF);
      float h1 = bf2f(hvpk[nn][0] >> 16);
      float h2 = bf2f(hvpk[nn][1] & 0xFFFF);
      float h3 = bf2f(hvpk[nn][1] >> 16);
      d[0] += fmaxf((h0 - mean[0]) * inv[0] * p.y + p.z, 0.f) * p.w;
      d[1] += fmaxf((h1 - mean[1]) * inv[1] * p.y + p.z, 0.f) * p.w;
      d[2] += fmaxf((h2 - mean[2]) * inv[2] * p.y + p.z, 0.f) * p.w;
      d[3] += fmaxf((h3 - mean[3]) * inv[3] * p.y + p.z, 0.f) * p.w;
    }
#pragma unroll
    for (int j = 0; j < 4; ++j) {
#pragma unroll
      for (int m = 1; m < 16; m <<= 1) d[j] += __shfl_xor(d[j], m, 64);
      if (low4 == 0) temp_w[e0 + hi * 4 + j] = d[j] + b2s;
    }
#pragma unroll
    for (int kk = 0; kk < 4; ++kk) a_cur[kk] = a_next[kk];
  }
}

// ============ gemm role (r15 body, 32 rows, 256 thr) ============
__device__ __forceinline__
void gemm_role(u16* Atile, const u16* __restrict__ Ab,
               const u16* __restrict__ pkW, u16* __restrict__ Cb, int gid) {
  int tid = threadIdx.x;
  int w = tid >> 6, lane = tid & 63, low4 = lane & 15, hi = lane >> 4;
  int row0 = gid * 32;

  const char* asrc = (const char*)(Ab + (size_t)row0 * 256);
#pragma unroll
  for (int i = 0; i < 4; ++i) {
    u32 d = (u32)(((i * 4 + w) * 64 + lane) * 16);
    GLOAD_LDS16(asrc + swz512(d), (char*)Atile + (i * 4 + w) * 1024);
  }

  floatx4 acc[2][4];
#pragma unroll
  for (int rt = 0; rt < 2; ++rt)
#pragma unroll
    for (int nn = 0; nn < 4; ++nn) acc[rt][nn] = (floatx4){0.f, 0.f, 0.f, 0.f};

  __syncthreads();

#pragma unroll
  for (int kt = 0; kt < 8; ++kt) {
    short8 bfr[4];
    const u16* pw = pkW + ((size_t)(kt * 16 + w * 4) * 64 + lane) * 8;
#pragma unroll
    for (int nn = 0; nn < 4; ++nn) bfr[nn] = *(const short8*)(pw + nn * 512);
    short8 afr[2];
#pragma unroll
    for (int rt = 0; rt < 2; ++rt) {
      u32 p = (u32)((rt * 16 + low4) * 512 + (kt * 32 + hi * 8) * 2);
      afr[rt] = *(const short8*)((const char*)Atile + swz512(p));
    }
#pragma unroll
    for (int rt = 0; rt < 2; ++rt)
#pragma unroll
      for (int nn = 0; nn < 4; ++nn)
        acc[rt][nn] = __builtin_amdgcn_mfma_f32_16x16x32_bf16(afr[rt], bfr[nn],
                                                              acc[rt][nn], 0, 0, 0);
  }
#pragma unroll
  for (int rt = 0; rt < 2; ++rt)
#pragma unroll
    for (int nn = 0; nn < 4; ++nn)
#pragma unroll
      for (int j = 0; j < 4; ++j) {
        int row = row0 + rt * 16 + hi * 4 + j;
        int col = w * 64 + nn * 16 + low4;
        Cb[(size_t)row * 256 + col] = (u16)bf16rn(acc[rt][nn][j]);
      }
}

// ============ scan role (256 threads) ============
__device__ __forceinline__
void scan_role(const int* __restrict__ cnt, int* __restrict__ base,
               int* __restrict__ cur, const float* __restrict__ deg,
               float* __restrict__ dis, int* part) {
  int tid = threadIdx.x;
  int per = kN >> 8;
  int i0 = tid * per;
  int s = 0;
  for (int k = 0; k < per; ++k) s += cnt[i0 + k];
  part[tid] = s;
  __syncthreads();
  for (int off = 1; off < 256; off <<= 1) {
    int v = (tid >= off) ? part[tid - off] : 0;
    __syncthreads();
    part[tid] += v;
    __syncthreads();
  }
  int run = (tid == 0) ? 0 : part[tid - 1];
  for (int k = 0; k < per; ++k) {
    base[i0 + k] = run; cur[i0 + k] = run; run += cnt[i0 + k];
    float d = deg[i0 + k] + 1.0f;
    dis[i0 + k] = (d > 0.f) ? rsqrtf(d) : 0.f;
  }
  if (tid == 255) base[kN] = run;
}

// ===== L2b: gemm1 ∥ scan_b ∥ temporal edge-prep (256 thr, round-striped) ====
__global__ __launch_bounds__(256)
void k_gemm1_l3(const u16* __restrict__ xb, const u16* __restrict__ pkb,
                u16* __restrict__ hb, const int* __restrict__ cnt_b,
                int* __restrict__ base_b, int* __restrict__ cur_b,
                const float* __restrict__ deg_b, float* __restrict__ dis_b,
                const int* __restrict__ tcol, const float* __restrict__ tmpw,
                float* __restrict__ deg_t, int* __restrict__ cnt_t) {
  __shared__ __align__(16) u16 Atile[32 * 256];   // 16 KB (scan reuses as part[])
  int bid = blockIdx.x;
  if (bid == 1536) {                          // scan_b
    scan_role(cnt_b, base_b, cur_b, deg_b, dis_b, (int*)Atile);
    return;
  }
  int r = bid >> 8, idx = bid & 255;
  if (r == 0 || r == 2) {                     // 512 gemm blocks
    gemm_role(Atile, xb, pkb, hb, idx + (r == 2 ? 256 : 0));
  } else {                                    // prep_t rounds {1,3,4,5}: 1024
    int prepord = (r == 1) ? 0 : r - 2;
    int eid = (prepord * 256 + idx) * 256 + threadIdx.x;
    int c = tcol[eid];
    atomicAdd(&deg_t[c], tmpw[eid]);
    atomicAdd(&cnt_t[c], 1);
  }
}

// ============ agg role: 32 lanes/node, 8 nodes per 256-thread block ============
template <int FINAL>
__device__ __forceinline__
void agg_role(const u16* __restrict__ h, const void* __restrict__ residv,
              const float* __restrict__ x0, const int2* __restrict__ csr,
              const int* __restrict__ basep, const float* __restrict__ dis,
              const float* __restrict__ bias, const float* __restrict__ g1,
              const float* __restrict__ b1, const float* __restrict__ g2,
              const float* __restrict__ b2, void* __restrict__ outv, int aid) {
  int tid = threadIdx.x;
  int sub = tid >> 5, lane = tid & 31;
  int node = aid * 8 + sub;
  int c = lane * 8;
  const u16* hcol = h + c;
  float di = dis[node];
  float sl = di * di;
  float acc[8];
  {
    uint4 u = *(const uint4*)(hcol + (size_t)node * HN);
    float f[8]; ub8(u, f);
#pragma unroll
    for (int i = 0; i < 8; ++i) acc[i] = f[i] * sl;
  }
  int e0 = basep[node], e1 = basep[node + 1];
  int k = e0;
  for (; k + 4 <= e1; k += 4) {
    int2 p0 = csr[k], p1 = csr[k + 1], p2 = csr[k + 2], p3 = csr[k + 3];
    uint4 u0 = *(const uint4*)(hcol + (size_t)p0.x * HN);
    uint4 u1 = *(const uint4*)(hcol + (size_t)p1.x * HN);
    uint4 u2 = *(const uint4*)(hcol + (size_t)p2.x * HN);
    uint4 u3 = *(const uint4*)(hcol + (size_t)p3.x * HN);
    float n0 = __int_as_float(p0.y), n1 = __int_as_float(p1.y);
    float n2 = __int_as_float(p2.y), n3 = __int_as_float(p3.y);
    float f0[8], f1[8], f2[8], f3[8];
    ub8(u0, f0); ub8(u1, f1); ub8(u2, f2); ub8(u3, f3);
#pragma unroll
    for (int i = 0; i < 8; ++i)
      acc[i] += n0 * f0[i] + n1 * f1[i] + n2 * f2[i] + n3 * f3[i];
  }
  for (; k < e1; ++k) {
    int2 p = csr[k];
    uint4 u = *(const uint4*)(hcol + (size_t)p.x * HN);
    float nf = __int_as_float(p.y);
    float f[8]; ub8(u, f);
#pragma unroll
    for (int i = 0; i < 8; ++i) acc[i] += nf * f[i];
  }
  float v[8];
  {
    float4 b0 = *(const float4*)(bias + c);
    float4 b4 = *(const float4*)(bias + c + 4);
    float bb[8] = {b0.x, b0.y, b0.z, b0.w, b4.x, b4.y, b4.z, b4.w};
    float rr[8];
    if (!FINAL) {
      const float* rp = (const float*)residv + (size_t)node * HN + c;
      float4 r0 = *(const float4*)rp;
      float4 r4 = *(const float4*)(rp + 4);
      rr[0] = r0.x; rr[1] = r0.y; rr[2] = r0.z; rr[3] = r0.w;
      rr[4] = r4.x; rr[5] = r4.y; rr[6] = r4.z; rr[7] = r4.w;
    } else {
      uint4 u = *(const uint4*)((const u16*)residv + (size_t)node * HN + c);
      ub8(u, rr);
    }
#pragma unroll
    for (int i = 0; i < 8; ++i) v[i] = acc[i] + bb[i] + rr[i];
  }
  float s1 = 0.f, s2 = 0.f;
#pragma unroll
  for (int i = 0; i < 8; ++i) { s1 += v[i]; s2 += v[i] * v[i]; }
#pragma unroll
  for (int m = 1; m < 32; m <<= 1) {
    s1 += __shfl_xor(s1, m, 64);
    s2 += __shfl_xor(s2, m, 64);
  }
  float mean = s1 * (1.f / HN);
  float inv = rsqrtf(s2 * (1.f / HN) - mean * mean + kEps);
  float4 ga = *(const float4*)(g1 + c);
  float4 gb = *(const float4*)(g1 + c + 4);
  float4 ba = *(const float4*)(b1 + c);
  float4 bbv = *(const float4*)(b1 + c + 4);
  float gg[8] = {ga.x, ga.y, ga.z, ga.w, gb.x, gb.y, gb.z, gb.w};
  float bt[8] = {ba.x, ba.y, ba.z, ba.w, bbv.x, bbv.y, bbv.z, bbv.w};
  float y[8];
#pragma unroll
  for (int i = 0; i < 8; ++i)
    y[i] = fmaxf((v[i] - mean) * inv * gg[i] + bt[i], 0.f);
  if (!FINAL) {
    uint4 o = make_uint4(cvtpk(y[0], y[1]), cvtpk(y[2], y[3]),
                         cvtpk(y[4], y[5]), cvtpk(y[6], y[7]));
    *(uint4*)((u16*)outv + (size_t)node * HN + c) = o;
  } else {
    const float* xp = x0 + (size_t)node * HN + c;
    float4 x0v = *(const float4*)xp;
    float4 x4v = *(const float4*)(xp + 4);
    float xx[8] = {x0v.x, x0v.y, x0v.z, x0v.w, x4v.x, x4v.y, x4v.z, x4v.w};
    float z[8];
    float t1 = 0.f, t2 = 0.f;
#pragma unroll
    for (int i = 0; i < 8; ++i) {
      z[i] = y[i] + xx[i];
      t1 += z[i]; t2 += z[i] * z[i];
    }
#pragma unroll
    for (int m = 1; m < 32; m <<= 1) {
      t1 += __shfl_xor(t1, m, 64);
      t2 += __shfl_xor(t2, m, 64);
    }
    float m2 = t1 * (1.f / HN);
    float i2 = rsqrtf(t2 * (1.f / HN) - m2 * m2 + kEps);
    float4 Ga = *(const float4*)(g2 + c);
    float4 Gb = *(const float4*)(g2 + c + 4);
    float4 Ba = *(const float4*)(b2 + c);
    float4 Bb = *(const float4*)(b2 + c + 4);
    float G[8] = {Ga.x, Ga.y, Ga.z, Ga.w, Gb.x, Gb.y, Gb.z, Gb.w};
    float B[8] = {Ba.x, Ba.y, Ba.z, Ba.w, Bb.x, Bb.y, Bb.z, Bb.w};
    float* op = (float*)outv + (size_t)node * HN + c;
    *(float4*)op = make_float4((z[0] - m2) * i2 * G[0] + B[0],
                               (z[1] - m2) * i2 * G[1] + B[1],
                               (z[2] - m2) * i2 * G[2] + B[2],
                               (z[3] - m2) * i2 * G[3] + B[3]);
    *(float4*)(op + 4) = make_float4((z[4] - m2) * i2 * G[4] + B[4],
                                     (z[5] - m2) * i2 * G[5] + B[5],
                                     (z[6] - m2) * i2 * G[6] + B[6],
                                     (z[7] - m2) * i2 * G[7] + B[7]);
  }
}

// ================= L4: fill_b ∥ scan_t =================
__global__ __launch_bounds__(256)
void k_fillb_scant(const int* __restrict__ bei, const float* __restrict__ bw,
                   const float* __restrict__ dis_b, int* __restrict__ cur_b,
                   int2* __restrict__ csr_b, const int* __restrict__ cnt_t,
                   int* __restrict__ base_t, int* __restrict__ cur_t,
                   const float* __restrict__ deg_t, float* __restrict__ dis_t) {
  __shared__ int part[256];
  if (blockIdx.x == 0) {
    scan_role(cnt_t, base_t, cur_t, deg_t, dis_t, part);
  } else {
    int eid = (blockIdx.x - 1) * 256 + threadIdx.x;
    int rr = bei[eid], c = bei[kEB + eid];
    float nrm = dis_b[rr] * bw[eid] * dis_b[c];
    int pos = atomicAdd(&cur_b[c], 1);
    csr_b[pos] = make_int2(rr, __float_as_int(nrm));
  }
}

// ================= L5: agg0 ∥ fill_t (round-striped) =================
__global__ __launch_bounds__(256)
void k_agg0_fillt(const u16* __restrict__ hb, const float* __restrict__ x,
                  const int2* __restrict__ csr_b, const int* __restrict__ base_b,
                  const float* __restrict__ dis_b, const float* __restrict__ bbias,
                  const float* __restrict__ gs, const float* __restrict__ bs,
                  u16* __restrict__ sb, const int* __restrict__ tei,
                  const float* __restrict__ tmpw, const float* __restrict__ dis_t,
                  int* __restrict__ cur_t, int2* __restrict__ csr_t) {
  int bid = blockIdx.x;
  int r = bid >> 8, idx = bid & 255;
  if (r % 3 == 1) {                           // 4 rounds x 256 = 1024 fill blocks
    int eid = ((r / 3) * 256 + idx) * 256 + threadIdx.x;
    int rr = tei[eid], c = tei[kET + eid];
    float nrm = dis_t[rr] * tmpw[eid] * dis_t[c];
    int pos = atomicAdd(&cur_t[c], 1);
    csr_t[pos] = make_int2(rr, __float_as_int(nrm));
  } else {                                    // 8 rounds x 256 = 2048 agg blocks
    int agg_ord = r - r / 3 - (r % 3 == 2 ? 1 : 0);
    agg_role<0>(hb, x, nullptr, csr_b, base_b, dis_b, bbias, gs, bs,
                nullptr, nullptr, sb, agg_ord * 256 + idx);
  }
}

// ============ L6: gemm2 (standalone) ============
__global__ __launch_bounds__(256)
void k_gemm_mfma(const u16* __restrict__ Ab, const u16* __restrict__ pkW,
                 u16* __restrict__ Cb) {
  __shared__ __align__(16) u16 Atile[32 * 256];
  gemm_role(Atile, Ab, pkW, Cb, blockIdx.x);
}

// ================= L7: agg1 (final) =================
__global__ __launch_bounds__(256)
void k_agg1(const u16* __restrict__ h, const u16* __restrict__ sb,
            const float* __restrict__ x0, const int2* __restrict__ csr,
            const int* __restrict__ basep, const float* __restrict__ dis,
            const float* __restrict__ bias, const float* __restrict__ g1,
            const float* __restrict__ b1, const float* __restrict__ g2,
            const float* __restrict__ b2, float* __restrict__ outp) {
  agg_role<1>(h, sb, x0, csr, basep, dis, bias, g1, b1, g2, b2, outp, blockIdx.x);
}

extern "C" void kernel_launch(void* const* d_in, const int* in_sizes, int n_in,
                              void* d_out, int out_size, void* d_ws, size_t ws_size,
                              hipStream_t stream) {
  const float* x     = (const float*)d_in[0];
  const int*   bei   = (const int*)d_in[1];
  const float* bew   = (const float*)d_in[2];
  const int*   tei   = (const int*)d_in[3];
  const float* tattr = (const float*)d_in[4];
  const float* Wb    = (const float*)d_in[5];
  const float* bb    = (const float*)d_in[6];
  const float* Wt    = (const float*)d_in[7];
  const float* bt    = (const float*)d_in[8];
  const float* gs    = (const float*)d_in[9];
  const float* bs    = (const float*)d_in[10];
  const float* gt    = (const float*)d_in[11];
  const float* btn   = (const float*)d_in[12];
  const float* pw1   = (const float*)d_in[13];
  const float* pb1   = (const float*)d_in[14];
  const float* pg    = (const float*)d_in[15];
  const float* pbeta = (const float*)d_in[16];
  const float* pw2   = (const float*)d_in[17];
  const float* pb2   = (const float*)d_in[18];
  float* outp = (float*)d_out;

  size_t off = 0;
  auto alloc = [&](size_t bytes) -> void* {
    void* p = (char*)d_ws + off;
    off += (bytes + 255) & ~(size_t)255;
    return p;
  };
  float* deg_b = (float*)alloc(kN * 4);
  float* deg_t = (float*)alloc(kN * 4);
  int*   cnt_b = (int*)alloc(kN * 4);
  int*   cnt_t = (int*)alloc(kN * 4);       // deg_b..cnt_t contiguous: zero-role
  float* dis_b = (float*)alloc(kN * 4);
  float* dis_t = (float*)alloc(kN * 4);
  int*   base_b = (int*)alloc((kN + 1) * 4);
  int*   base_t = (int*)alloc((kN + 1) * 4);
  int*   cur_b  = (int*)alloc(kN * 4);
  int*   cur_t  = (int*)alloc(kN * 4);
  float* tmpw   = (float*)alloc(kET * 4);
  int2*  csr_b  = (int2*)alloc((size_t)kEB * 8);
  int2*  csr_t  = (int2*)alloc((size_t)kET * 8);
  u16*   pk1 = (u16*)alloc(32768 * 2);
  u16*   pkb = (u16*)alloc(65536 * 2);
  u16*   pkt = (u16*)alloc(65536 * 2);
  float4* pp = (float4*)alloc(256 * 16);
  u16*   xb  = (u16*)alloc((size_t)kN * HN * 2);
  u16*   hb  = (u16*)alloc((size_t)kN * HN * 2);
  u16*   sb  = (u16*)alloc((size_t)kN * HN * 2);
  (void)ws_size; (void)in_sizes; (void)n_in; (void)out_size;

  // L1: pack ∥ cvt ∥ zero(deg_b..cnt_t)
  k_prep_const<<<2753, 256, 0, stream>>>(pw1, Wb, Wt, pb1, pg, pbeta, pw2,
                                         pk1, pkb, pkt, pp, x, xb,
                                         (uint4*)deg_b);
  // L2a: proj ∥ bold edge-prep
  k_proj_prepb<<<1536, 512, 0, stream>>>(tattr, pk1, pb1, pp, pb2, tmpw,
                                         bei + kEB, bew, deg_b, cnt_b);
  // L2b: gemm1 ∥ scan_b ∥ temporal edge-prep
  k_gemm1_l3<<<1537, 256, 0, stream>>>(xb, pkb, hb, cnt_b, base_b, cur_b,
                                       deg_b, dis_b, tei + kET, tmpw,
                                       deg_t, cnt_t);
  // L4: fill_b ∥ scan_t
  k_fillb_scant<<<1 + kEB / 256, 256, 0, stream>>>(bei, bew, dis_b, cur_b, csr_b,
                                                   cnt_t, base_t, cur_t,
                                                   deg_t, dis_t);
  // L5: agg0 ∥ fill_t
  k_agg0_fillt<<<3072, 256, 0, stream>>>(hb, x, csr_b, base_b, dis_b, bb, gs, bs,
                                         sb, tei, tmpw, dis_t, cur_t, csr_t);
  // L6: gemm2
  k_gemm_mfma<<<kN / 32, 256, 0, stream>>>(sb, pkt, hb);
  // L7: agg1 + final LN
  k_agg1<<<kN / 8, 256, 0, stream>>>(hb, sb, x, csr_t, base_t, dis_t,
                                     bt, gt, btn, gs, bs, outp);
}